// Round 5
// baseline (379.816 us; speedup 1.0000x reference)
//
#include <hip/hip_runtime.h>

#define BB 8
#define NN 2048
#define FIN 256
#define FO 64

typedef short short8_t __attribute__((ext_vector_type(8)));
typedef float float4_t __attribute__((ext_vector_type(4)));

__device__ __forceinline__ unsigned short f2bf(float x) {
  unsigned int u = __float_as_uint(x);
  unsigned int r = (u + 0x7fffu + ((u >> 16) & 1u)) >> 16;
  return (unsigned short)r;
}

// ---------------- K0: zero the column-sum accumulator -----------------------
__global__ __launch_bounds__(256) void k0_zero(float* __restrict__ scol) {
  scol[blockIdx.x * 256 + threadIdx.x] = 0.0f;
}

// ---------------- K1: Wh = h@W ; f1 = Wh@a1 ; f2 = Wh@a2 ; V = Wh*level ----
__global__ __launch_bounds__(256) void k1_gemm(
    const float* __restrict__ h,
    const float* __restrict__ level,
    const float* __restrict__ W,
    const float* __restrict__ a,
    float* __restrict__ V, float* __restrict__ f1, float* __restrict__ f2)
{
  __shared__ float hs[16 * 260];
  __shared__ float parts1[16 * 17];
  __shared__ float parts2[16 * 17];
  int t = threadIdx.x;
  int b = blockIdx.x >> 7;
  int i0 = (blockIdx.x & 127) * 16;

  {
    int r_ld = t >> 4, f0 = (t & 15) * 16;
    const float* hp = h + (size_t)(b * NN + i0 + r_ld) * FIN + f0;
    float4 x0 = *(const float4*)(hp);
    float4 x1 = *(const float4*)(hp + 4);
    float4 x2 = *(const float4*)(hp + 8);
    float4 x3 = *(const float4*)(hp + 12);
    float* hd = &hs[r_ld * 260 + f0];
    *(float4*)(hd + 0) = x0; *(float4*)(hd + 4) = x1;
    *(float4*)(hd + 8) = x2; *(float4*)(hd + 12) = x3;
  }
  __syncthreads();

  int r = t >> 4;
  int c4 = (t & 15) * 4;
  float4 acc = {0, 0, 0, 0};

  for (int f = 0; f < FIN; f += 8) {
    float4 hv0 = *(const float4*)&hs[r * 260 + f];
    float4 hv1 = *(const float4*)&hs[r * 260 + f + 4];
    float hvv[8] = {hv0.x, hv0.y, hv0.z, hv0.w, hv1.x, hv1.y, hv1.z, hv1.w};
    #pragma unroll
    for (int k = 0; k < 8; ++k) {
      float4 wv = *(const float4*)&W[(size_t)(f + k) * FO + c4];
      acc.x += hvv[k] * wv.x; acc.y += hvv[k] * wv.y;
      acc.z += hvv[k] * wv.z; acc.w += hvv[k] * wv.w;
    }
  }

  float p1 = acc.x * a[c4] + acc.y * a[c4 + 1] + acc.z * a[c4 + 2] + acc.w * a[c4 + 3];
  float p2 = acc.x * a[64 + c4] + acc.y * a[64 + c4 + 1] +
             acc.z * a[64 + c4 + 2] + acc.w * a[64 + c4 + 3];
  parts1[r * 17 + (t & 15)] = p1;
  parts2[r * 17 + (t & 15)] = p2;
  __syncthreads();
  if (t < 16) {
    float s1 = 0.f, s2 = 0.f;
    #pragma unroll
    for (int g = 0; g < 16; ++g) { s1 += parts1[t * 17 + g]; s2 += parts2[t * 17 + g]; }
    f1[b * NN + i0 + t] = s1;
    f2[b * NN + i0 + t] = s2;
  }

  float lv = level[b * NN + i0 + r];
  float4 vv = {acc.x * lv, acc.y * lv, acc.z * lv, acc.w * lv};
  *(float4*)&V[(size_t)(b * NN + i0 + r) * FO + c4] = vv;
}

// ---------------- K2a: partial column sums + u (or bitmask) -----------------
// grid 2048 (8 b x 256 8-row chunks), 256 threads. Each block reads 8 FULL
// rows of adj+node_type (16 KB contiguous per array) — every wave load is a
// 2 KB contiguous burst, every u write a 1 KB burst. Per-chunk LDS reduce,
// then atomicAdd partial column sums into scol[b][j].
template <int STORE_U>
__global__ __launch_bounds__(256) void k2a_stats(
    const int* __restrict__ adj,
    const float* __restrict__ ntp,
    const float* __restrict__ f1,
    const float* __restrict__ f2,
    unsigned short* __restrict__ u_bf,
    unsigned char* __restrict__ bits,
    float* __restrict__ scol)
{
  __shared__ float red[4 * 520];
  int t = threadIdx.x;
  int b = blockIdx.x >> 8;
  int i0 = (blockIdx.x & 255) * 8;
  int w = t >> 6, l = t & 63;

  #pragma unroll
  for (int c = 0; c < 4; ++c) {
    int j8 = c * 512 + l * 8;
    float4 f2lo = *(const float4*)(f2 + b * NN + j8);
    float4 f2hi = *(const float4*)(f2 + b * NN + j8 + 4);
    float f2v[8] = {f2lo.x, f2lo.y, f2lo.z, f2lo.w, f2hi.x, f2hi.y, f2hi.z, f2hi.w};
    float acc8[8] = {0, 0, 0, 0, 0, 0, 0, 0};

    #pragma unroll
    for (int r = 0; r < 2; ++r) {
      size_t base = (size_t)(b * NN + i0 + w * 2 + r);
      const int* ap = adj + base * NN + j8;
      int4 a0 = *(const int4*)ap;
      int4 a1 = *(const int4*)(ap + 4);
      const float* npp = ntp + base * NN + j8;
      float4 n0 = *(const float4*)npp;
      float4 n1 = *(const float4*)(npp + 4);
      float f1v = f1[base];
      float ntf[8] = {n0.x, n0.y, n0.z, n0.w, n1.x, n1.y, n1.z, n1.w};
      int am[8] = {a0.x, a0.y, a0.z, a0.w, a1.x, a1.y, a1.z, a1.w};
      float uv[8];
      unsigned int mb = 0;
      #pragma unroll
      for (int e = 0; e < 8; ++e) {
        float x = f1v + f2v[e];
        x = fmaxf(x, 0.2f * x);            // leaky_relu slope 0.2
        float E = x * ntf[e];
        bool m = am[e] > 0;
        float u = m ? __expf(E) : 0.0f;
        uv[e] = u;
        acc8[e] += u;
        mb |= (m ? 1u : 0u) << e;
      }
      if (STORE_U) {
        uint4 pk;
        pk.x = (unsigned int)f2bf(uv[0]) | ((unsigned int)f2bf(uv[1]) << 16);
        pk.y = (unsigned int)f2bf(uv[2]) | ((unsigned int)f2bf(uv[3]) << 16);
        pk.z = (unsigned int)f2bf(uv[4]) | ((unsigned int)f2bf(uv[5]) << 16);
        pk.w = (unsigned int)f2bf(uv[6]) | ((unsigned int)f2bf(uv[7]) << 16);
        *(uint4*)(u_bf + base * NN + j8) = pk;
      } else {
        bits[base * (NN / 8) + c * 64 + l] = (unsigned char)mb;
      }
    }

    #pragma unroll
    for (int e = 0; e < 8; ++e) red[w * 520 + l * 8 + e] = acc8[e];
    __syncthreads();
    {
      int j2 = t * 2;
      float s0 = 0.f, s1 = 0.f;
      #pragma unroll
      for (int ww = 0; ww < 4; ++ww) {
        float2 v = *(const float2*)&red[ww * 520 + j2];
        s0 += v.x; s1 += v.y;
      }
      atomicAdd(&scol[b * NN + c * 512 + j2], s0);
      atomicAdd(&scol[b * NN + c * 512 + j2 + 1], s1);
    }
    __syncthreads();
  }
}

// ---------------- K2b: pack V'[j][o]=V[j][o]/s_j into MFMA B-frag order -----
__global__ __launch_bounds__(256) void k2b_pack(
    const float* __restrict__ V,
    const float* __restrict__ scol,
    unsigned short* __restrict__ vf)
{
  int t = threadIdx.x;
  int b = blockIdx.x >> 6;
  int kk = blockIdx.x & 63;
  int ng = t >> 6;
  int l = t & 63;
  int jb = kk * 32 + ((l >> 4) * 8);
  int o = ng * 16 + (l & 15);
  unsigned int pk[4];
  #pragma unroll
  for (int p = 0; p < 4; ++p) {
    int jr0 = jb + 2 * p, jr1 = jb + 2 * p + 1;
    float s0 = scol[b * NN + jr0];
    float s1 = scol[b * NN + jr1];
    float i0 = (s0 > 0.f) ? (1.0f / s0) : 0.0f;
    float i1 = (s1 > 0.f) ? (1.0f / s1) : 0.0f;
    float v0 = V[(size_t)(b * NN + jr0) * FO + o] * i0;
    float v1 = V[(size_t)(b * NN + jr1) * FO + o] * i1;
    pk[p] = (unsigned int)f2bf(v0) | ((unsigned int)f2bf(v1) << 16);
  }
  *(uint4*)(vf + (size_t)(((b * 64 + kk) * 4 + ng) * 64 + l) * 8) =
      make_uint4(pk[0], pk[1], pk[2], pk[3]);
}

// ---------------- K3a: out = relu(U @ V'), U preloaded bf16 -----------------
__global__ __launch_bounds__(256) void k3_agg_u(
    const unsigned short* __restrict__ u_bf,
    const unsigned short* __restrict__ vf,
    float* __restrict__ outp)
{
  __shared__ float red[4 * 16 * 68];
  int t = threadIdx.x;
  int b = blockIdx.x >> 7;
  int i0 = (blockIdx.x & 127) * 16;
  int w = t >> 6, l = t & 63;
  int col = l & 15, quad = l >> 4;
  const unsigned short* urow = u_bf + (size_t)(b * NN + i0 + col) * NN + quad * 8;
  const unsigned short* vbase = vf + (size_t)(b * 64) * 2048 + l * 8;

  short8_t Aall[16];
  #pragma unroll
  for (int s = 0; s < 16; ++s)
    Aall[s] = *(const short8_t*)(urow + (size_t)(w * 16 + s) * 32);

  const unsigned short* vb0 = vbase + (size_t)(w * 16) * 2048;
  short8_t c0 = *(const short8_t*)(vb0);
  short8_t c1 = *(const short8_t*)(vb0 + 512);
  short8_t c2 = *(const short8_t*)(vb0 + 1024);
  short8_t c3 = *(const short8_t*)(vb0 + 1536);

  float4_t acc0 = {0, 0, 0, 0}, acc1 = {0, 0, 0, 0}, acc2 = {0, 0, 0, 0}, acc3 = {0, 0, 0, 0};

  #pragma unroll
  for (int s = 0; s < 16; ++s) {
    short8_t n0, n1, n2, n3;
    if (s < 15) {
      const unsigned short* vn = vbase + (size_t)(w * 16 + s + 1) * 2048;
      n0 = *(const short8_t*)(vn);
      n1 = *(const short8_t*)(vn + 512);
      n2 = *(const short8_t*)(vn + 1024);
      n3 = *(const short8_t*)(vn + 1536);
    }
    acc0 = __builtin_amdgcn_mfma_f32_16x16x32_bf16(Aall[s], c0, acc0, 0, 0, 0);
    acc1 = __builtin_amdgcn_mfma_f32_16x16x32_bf16(Aall[s], c1, acc1, 0, 0, 0);
    acc2 = __builtin_amdgcn_mfma_f32_16x16x32_bf16(Aall[s], c2, acc2, 0, 0, 0);
    acc3 = __builtin_amdgcn_mfma_f32_16x16x32_bf16(Aall[s], c3, acc3, 0, 0, 0);
    if (s < 15) { c0 = n0; c1 = n1; c2 = n2; c3 = n3; }
  }

  #pragma unroll
  for (int r = 0; r < 4; ++r) {
    int rowi = quad * 4 + r;
    red[w * 1088 + rowi * 68 + 0 + col] = acc0[r];
    red[w * 1088 + rowi * 68 + 16 + col] = acc1[r];
    red[w * 1088 + rowi * 68 + 32 + col] = acc2[r];
    red[w * 1088 + rowi * 68 + 48 + col] = acc3[r];
  }
  __syncthreads();

  int row = t >> 4, o4 = (t & 15) * 4;
  const float* rp = &red[row * 68 + o4];
  float4 s0 = *(const float4*)(rp);
  float4 s1 = *(const float4*)(rp + 1088);
  float4 s2 = *(const float4*)(rp + 2176);
  float4 s3 = *(const float4*)(rp + 3264);
  float4 o;
  o.x = fmaxf(s0.x + s1.x + s2.x + s3.x, 0.0f);
  o.y = fmaxf(s0.y + s1.y + s2.y + s3.y, 0.0f);
  o.z = fmaxf(s0.z + s1.z + s2.z + s3.z, 0.0f);
  o.w = fmaxf(s0.w + s1.w + s2.w + s3.w, 0.0f);
  *(float4*)&outp[(size_t)(b * NN + i0 + row) * FO + o4] = o;
}

// ---------------- K3b: fallback — recompute u from nt/f1/f2/bits -----------
__global__ __launch_bounds__(256) void k3_agg_b(
    const float* __restrict__ ntp,
    const unsigned char* __restrict__ bits,
    const float* __restrict__ f1,
    const float* __restrict__ f2,
    const unsigned short* __restrict__ vf,
    float* __restrict__ outp)
{
  __shared__ float red[4 * 16 * 68];
  int t = threadIdx.x;
  int b = blockIdx.x >> 7;
  int i0 = (blockIdx.x & 127) * 16;
  int w = t >> 6, l = t & 63;
  int col = l & 15, quad = l >> 4;
  int gi = b * NN + i0 + col;
  float f1v = f1[gi];
  const float* ntrow = ntp + (size_t)gi * NN;
  const unsigned char* brow = bits + (size_t)gi * (NN / 8);
  float4_t acc0 = {0, 0, 0, 0}, acc1 = {0, 0, 0, 0}, acc2 = {0, 0, 0, 0}, acc3 = {0, 0, 0, 0};

  for (int s = 0; s < 16; ++s) {
    int kk = w * 16 + s;
    int jq = kk * 32 + quad * 8;
    unsigned int m8 = brow[jq >> 3];
    float4 n0 = *(const float4*)(ntrow + jq);
    float4 n1 = *(const float4*)(ntrow + jq + 4);
    float4 g0 = *(const float4*)(f2 + b * NN + jq);
    float4 g1 = *(const float4*)(f2 + b * NN + jq + 4);
    float f2v[8] = {g0.x, g0.y, g0.z, g0.w, g1.x, g1.y, g1.z, g1.w};
    float ntf[8] = {n0.x, n0.y, n0.z, n0.w, n1.x, n1.y, n1.z, n1.w};
    union { unsigned int u[4]; short8_t v; } A;
    #pragma unroll
    for (int p = 0; p < 4; ++p) {
      int e0 = 2 * p, e1 = 2 * p + 1;
      float x0 = f1v + f2v[e0]; x0 = fmaxf(x0, 0.2f * x0);
      float u0 = ((m8 >> e0) & 1u) ? __expf(x0 * ntf[e0]) : 0.0f;
      float x1 = f1v + f2v[e1]; x1 = fmaxf(x1, 0.2f * x1);
      float u1 = ((m8 >> e1) & 1u) ? __expf(x1 * ntf[e1]) : 0.0f;
      A.u[p] = (unsigned int)f2bf(u0) | ((unsigned int)f2bf(u1) << 16);
    }
    const unsigned short* vb = vf + (size_t)(b * 64 + kk) * 2048 + l * 8;
    short8_t bf0 = *(const short8_t*)(vb);
    short8_t bf1 = *(const short8_t*)(vb + 512);
    short8_t bf2 = *(const short8_t*)(vb + 1024);
    short8_t bf3 = *(const short8_t*)(vb + 1536);
    acc0 = __builtin_amdgcn_mfma_f32_16x16x32_bf16(A.v, bf0, acc0, 0, 0, 0);
    acc1 = __builtin_amdgcn_mfma_f32_16x16x32_bf16(A.v, bf1, acc1, 0, 0, 0);
    acc2 = __builtin_amdgcn_mfma_f32_16x16x32_bf16(A.v, bf2, acc2, 0, 0, 0);
    acc3 = __builtin_amdgcn_mfma_f32_16x16x32_bf16(A.v, bf3, acc3, 0, 0, 0);
  }

  #pragma unroll
  for (int r = 0; r < 4; ++r) {
    int rowi = quad * 4 + r;
    red[w * 1088 + rowi * 68 + 0 + col] = acc0[r];
    red[w * 1088 + rowi * 68 + 16 + col] = acc1[r];
    red[w * 1088 + rowi * 68 + 32 + col] = acc2[r];
    red[w * 1088 + rowi * 68 + 48 + col] = acc3[r];
  }
  __syncthreads();

  int row = t >> 4, o4 = (t & 15) * 4;
  const float* rp = &red[row * 68 + o4];
  float4 s0 = *(const float4*)(rp);
  float4 s1 = *(const float4*)(rp + 1088);
  float4 s2 = *(const float4*)(rp + 2176);
  float4 s3 = *(const float4*)(rp + 3264);
  float4 o;
  o.x = fmaxf(s0.x + s1.x + s2.x + s3.x, 0.0f);
  o.y = fmaxf(s0.y + s1.y + s2.y + s3.y, 0.0f);
  o.z = fmaxf(s0.z + s1.z + s2.z + s3.z, 0.0f);
  o.w = fmaxf(s0.w + s1.w + s2.w + s3.w, 0.0f);
  *(float4*)&outp[(size_t)(b * NN + i0 + row) * FO + o4] = o;
}

extern "C" void kernel_launch(void* const* d_in, const int* in_sizes, int n_in,
                              void* d_out, int out_size, void* d_ws, size_t ws_size,
                              hipStream_t stream) {
  const float* h = (const float*)d_in[0];       // fp32 [B,N,FIN]
  const int* adj = (const int*)d_in[1];         // int32 [B,N,N]
  const float* level = (const float*)d_in[2];   // fp32 [B,N]
  const float* ntm = (const float*)d_in[3];     // fp32 [B,N,N]
  const float* W = (const float*)d_in[4];       // fp32 [FIN,FO]
  const float* a = (const float*)d_in[5];       // fp32 [2*FO,1]
  float* outp = (float*)d_out;

  float* V = (float*)d_ws;                              // 4 MB
  float* f1 = V + (size_t)BB * NN * FO;                 // 64 KB
  float* f2 = f1 + BB * NN;                             // 64 KB
  float* scol = f2 + BB * NN;                           // 64 KB
  unsigned short* vf = (unsigned short*)(scol + BB * NN); // 2 MB
  char* tail = (char*)(vf + (size_t)BB * NN * FO);
  size_t fixed = (size_t)(tail - (char*)d_ws);
  size_t need_u = fixed + (size_t)BB * NN * NN * 2;     // + 67 MB
  bool big = (ws_size >= need_u);

  k0_zero<<<64, 256, 0, stream>>>(scol);
  k1_gemm<<<1024, 256, 0, stream>>>(h, level, W, a, V, f1, f2);
  if (big) {
    unsigned short* u_bf = (unsigned short*)tail;
    k2a_stats<1><<<2048, 256, 0, stream>>>(adj, ntm, f1, f2, u_bf, nullptr, scol);
    k2b_pack<<<512, 256, 0, stream>>>(V, scol, vf);
    k3_agg_u<<<1024, 256, 0, stream>>>(u_bf, vf, outp);
  } else {
    unsigned char* bits = (unsigned char*)tail;         // + 4 MB
    k2a_stats<0><<<2048, 256, 0, stream>>>(adj, ntm, f1, f2, nullptr, bits, scol);
    k2b_pack<<<512, 256, 0, stream>>>(V, scol, vf);
    k3_agg_b<<<1024, 256, 0, stream>>>(ntm, bits, f1, f2, vf, outp);
  }
}

// Round 6
// 349.285 us; speedup vs baseline: 1.0874x; 1.0874x over previous
//
#include <hip/hip_runtime.h>

#define BB 8
#define NN 2048
#define FIN 256
#define FO 64

typedef short short8_t __attribute__((ext_vector_type(8)));
typedef float float4_t __attribute__((ext_vector_type(4)));

__device__ __forceinline__ unsigned short f2bf(float x) {
  unsigned int u = __float_as_uint(x);
  unsigned int r = (u + 0x7fffu + ((u >> 16) & 1u)) >> 16;
  return (unsigned short)r;
}

#define GLD16(gp, lp)                                                          \
  __builtin_amdgcn_global_load_lds(                                            \
      (const __attribute__((address_space(1))) void*)(gp),                     \
      (__attribute__((address_space(3))) void*)(lp), 16, 0, 0)

// ---------------- K0: zero the column-sum accumulator -----------------------
__global__ __launch_bounds__(256) void k0_zero(float* __restrict__ scol) {
  scol[blockIdx.x * 256 + threadIdx.x] = 0.0f;
}

// ---------------- K1: Wh = h@W ; f1 = Wh@a1 ; f2 = Wh@a2 ; V = Wh*level ----
// W staged in LDS in two 32-KB halves (removes serialized per-thread L2
// loads); h tile in LDS. 1024 blocks, 256 threads, ~51 KB LDS -> 3 blk/CU.
__global__ __launch_bounds__(256) void k1_gemm(
    const float* __restrict__ h,
    const float* __restrict__ level,
    const float* __restrict__ W,
    const float* __restrict__ a,
    float* __restrict__ V, float* __restrict__ f1, float* __restrict__ f2)
{
  __shared__ float wlds[128 * 64];   // 32 KB (one half of W)
  __shared__ float hs[16 * 260];
  __shared__ float parts1[16 * 17];
  __shared__ float parts2[16 * 17];
  int t = threadIdx.x;
  int b = blockIdx.x >> 7;
  int i0 = (blockIdx.x & 127) * 16;

  {
    int r_ld = t >> 4, f0 = (t & 15) * 16;
    const float* hp = h + (size_t)(b * NN + i0 + r_ld) * FIN + f0;
    float4 x0 = *(const float4*)(hp);
    float4 x1 = *(const float4*)(hp + 4);
    float4 x2 = *(const float4*)(hp + 8);
    float4 x3 = *(const float4*)(hp + 12);
    float* hd = &hs[r_ld * 260 + f0];
    *(float4*)(hd + 0) = x0; *(float4*)(hd + 4) = x1;
    *(float4*)(hd + 8) = x2; *(float4*)(hd + 12) = x3;
  }

  int r = t >> 4;
  int c4 = (t & 15) * 4;
  float4 acc = {0, 0, 0, 0};

  #pragma unroll
  for (int half = 0; half < 2; ++half) {
    __syncthreads();  // hs ready (iter 0) / wlds readers done (iter 1)
    #pragma unroll
    for (int q = 0; q < 8; ++q) {
      int idx = q * 1024 + t * 4;
      *(float4*)&wlds[idx] = *(const float4*)&W[half * 8192 + idx];
    }
    __syncthreads();
    for (int f = 0; f < 128; f += 8) {
      float4 hv0 = *(const float4*)&hs[r * 260 + half * 128 + f];
      float4 hv1 = *(const float4*)&hs[r * 260 + half * 128 + f + 4];
      float hvv[8] = {hv0.x, hv0.y, hv0.z, hv0.w, hv1.x, hv1.y, hv1.z, hv1.w};
      #pragma unroll
      for (int k = 0; k < 8; ++k) {
        float4 wv = *(const float4*)&wlds[(f + k) * 64 + c4];
        acc.x += hvv[k] * wv.x; acc.y += hvv[k] * wv.y;
        acc.z += hvv[k] * wv.z; acc.w += hvv[k] * wv.w;
      }
    }
  }

  float p1 = acc.x * a[c4] + acc.y * a[c4 + 1] + acc.z * a[c4 + 2] + acc.w * a[c4 + 3];
  float p2 = acc.x * a[64 + c4] + acc.y * a[64 + c4 + 1] +
             acc.z * a[64 + c4 + 2] + acc.w * a[64 + c4 + 3];
  parts1[r * 17 + (t & 15)] = p1;
  parts2[r * 17 + (t & 15)] = p2;
  __syncthreads();
  if (t < 16) {
    float s1 = 0.f, s2 = 0.f;
    #pragma unroll
    for (int g = 0; g < 16; ++g) { s1 += parts1[t * 17 + g]; s2 += parts2[t * 17 + g]; }
    f1[b * NN + i0 + t] = s1;
    f2[b * NN + i0 + t] = s2;
  }

  float lv = level[b * NN + i0 + r];
  float4 vv = {acc.x * lv, acc.y * lv, acc.z * lv, acc.w * lv};
  *(float4*)&V[(size_t)(b * NN + i0 + r) * FO + c4] = vv;
}

// ---------------- K2a: DMA-staged column sums + u (or bitmask) --------------
// grid 2048 (8 b x 256 8-row blocks), 256 threads. adj+ntp staged into LDS
// via global_load_lds (no VGPR round-trip -> deep DMA queue), double-buffered
// 256-col chunks. Wave w owns rows {2w,2w+1}; lane l owns cols 64k+l.
template <int STORE_U>
__global__ __launch_bounds__(256) void k2a_stats(
    const int* __restrict__ adj,
    const float* __restrict__ ntp,
    const float* __restrict__ f1,
    const float* __restrict__ f2,
    unsigned short* __restrict__ u_bf,
    unsigned char* __restrict__ bits,
    float* __restrict__ scol)
{
  __shared__ int ladj[2][8 * 256];   // 16 KB
  __shared__ float lnt[2][8 * 256];  // 16 KB
  __shared__ float red[4 * 264];     // 4.2 KB
  int t = threadIdx.x;
  int b = blockIdx.x >> 8;
  int i0 = (blockIdx.x & 255) * 8;
  int w = t >> 6, l = t & 63;
  size_t rbase = (size_t)(b * NN + i0);
  int r0 = 2 * w;

  // stage chunk c into buffer buf: wave w stages its own rows (2w, 2w+1)
  auto stage = [&](int buf, int c) {
    #pragma unroll
    for (int r = 0; r < 2; ++r) {
      int row = r0 + r;
      const int* ga = adj + (rbase + row) * NN + c * 256 + l * 4;
      const float* gn = ntp + (rbase + row) * NN + c * 256 + l * 4;
      GLD16(ga, &ladj[buf][row * 256]);
      GLD16(gn, &lnt[buf][row * 256]);
    }
  };

  stage(0, 0);

  float f1v0 = f1[rbase + r0];
  float f1v1 = f1[rbase + r0 + 1];
  float f2all[32];
  #pragma unroll
  for (int c = 0; c < 8; ++c)
    #pragma unroll
    for (int k = 0; k < 4; ++k)
      f2all[c * 4 + k] = f2[b * NN + c * 256 + 64 * k + l];

  for (int c = 0; c < 8; ++c) {
    int cur = c & 1;
    __syncthreads();  // (1) DMA for chunk c complete; red free

    float acc4[4] = {0, 0, 0, 0};
    #pragma unroll
    for (int r = 0; r < 2; ++r) {
      int row = r0 + r;
      float f1v = r ? f1v1 : f1v0;
      #pragma unroll
      for (int k = 0; k < 4; ++k) {
        int av = ladj[cur][row * 256 + 64 * k + l];
        float nv = lnt[cur][row * 256 + 64 * k + l];
        float x = f1v + f2all[c * 4 + k];
        x = fmaxf(x, 0.2f * x);            // leaky_relu slope 0.2
        bool m = av > 0;
        float u = m ? __expf(x * nv) : 0.0f;
        acc4[k] += u;
        if (STORE_U) {
          u_bf[(rbase + row) * NN + c * 256 + 64 * k + l] = f2bf(u);
        } else {
          unsigned long long bal = __ballot(m);
          if (l == 0)
            *(unsigned long long*)&bits[(rbase + row) * (NN / 8) + c * 32 + k * 8] = bal;
        }
      }
    }
    #pragma unroll
    for (int k = 0; k < 4; ++k) red[w * 264 + 64 * k + l] = acc4[k];
    __syncthreads();  // (2) red visible; compute done -> other buffer free

    if (c < 7) stage(cur ^ 1, c + 1);

    float s = red[0 * 264 + t % 256] + red[1 * 264 + t] + red[2 * 264 + t] + red[3 * 264 + t];
    atomicAdd(&scol[b * NN + c * 256 + t], s);
  }
}

// ---------------- K2b: pack V'[j][o]=V[j][o]/s_j into MFMA B-frag order -----
__global__ __launch_bounds__(256) void k2b_pack(
    const float* __restrict__ V,
    const float* __restrict__ scol,
    unsigned short* __restrict__ vf)
{
  int t = threadIdx.x;
  int b = blockIdx.x >> 6;
  int kk = blockIdx.x & 63;
  int ng = t >> 6;
  int l = t & 63;
  int jb = kk * 32 + ((l >> 4) * 8);
  int o = ng * 16 + (l & 15);
  unsigned int pk[4];
  #pragma unroll
  for (int p = 0; p < 4; ++p) {
    int jr0 = jb + 2 * p, jr1 = jb + 2 * p + 1;
    float s0 = scol[b * NN + jr0];
    float s1 = scol[b * NN + jr1];
    float i0 = (s0 > 0.f) ? (1.0f / s0) : 0.0f;
    float i1 = (s1 > 0.f) ? (1.0f / s1) : 0.0f;
    float v0 = V[(size_t)(b * NN + jr0) * FO + o] * i0;
    float v1 = V[(size_t)(b * NN + jr1) * FO + o] * i1;
    pk[p] = (unsigned int)f2bf(v0) | ((unsigned int)f2bf(v1) << 16);
  }
  *(uint4*)(vf + (size_t)(((b * 64 + kk) * 4 + ng) * 64 + l) * 8) =
      make_uint4(pk[0], pk[1], pk[2], pk[3]);
}

// ---------------- K3a: out = relu(U @ V'), U preloaded bf16 -----------------
__global__ __launch_bounds__(256) void k3_agg_u(
    const unsigned short* __restrict__ u_bf,
    const unsigned short* __restrict__ vf,
    float* __restrict__ outp)
{
  __shared__ float red[4 * 16 * 68];
  int t = threadIdx.x;
  int b = blockIdx.x >> 7;
  int i0 = (blockIdx.x & 127) * 16;
  int w = t >> 6, l = t & 63;
  int col = l & 15, quad = l >> 4;
  const unsigned short* urow = u_bf + (size_t)(b * NN + i0 + col) * NN + quad * 8;
  const unsigned short* vbase = vf + (size_t)(b * 64) * 2048 + l * 8;

  short8_t Aall[16];
  #pragma unroll
  for (int s = 0; s < 16; ++s)
    Aall[s] = *(const short8_t*)(urow + (size_t)(w * 16 + s) * 32);

  const unsigned short* vb0 = vbase + (size_t)(w * 16) * 2048;
  short8_t c0 = *(const short8_t*)(vb0);
  short8_t c1 = *(const short8_t*)(vb0 + 512);
  short8_t c2 = *(const short8_t*)(vb0 + 1024);
  short8_t c3 = *(const short8_t*)(vb0 + 1536);

  float4_t acc0 = {0, 0, 0, 0}, acc1 = {0, 0, 0, 0}, acc2 = {0, 0, 0, 0}, acc3 = {0, 0, 0, 0};

  #pragma unroll
  for (int s = 0; s < 16; ++s) {
    short8_t n0, n1, n2, n3;
    if (s < 15) {
      const unsigned short* vn = vbase + (size_t)(w * 16 + s + 1) * 2048;
      n0 = *(const short8_t*)(vn);
      n1 = *(const short8_t*)(vn + 512);
      n2 = *(const short8_t*)(vn + 1024);
      n3 = *(const short8_t*)(vn + 1536);
    }
    acc0 = __builtin_amdgcn_mfma_f32_16x16x32_bf16(Aall[s], c0, acc0, 0, 0, 0);
    acc1 = __builtin_amdgcn_mfma_f32_16x16x32_bf16(Aall[s], c1, acc1, 0, 0, 0);
    acc2 = __builtin_amdgcn_mfma_f32_16x16x32_bf16(Aall[s], c2, acc2, 0, 0, 0);
    acc3 = __builtin_amdgcn_mfma_f32_16x16x32_bf16(Aall[s], c3, acc3, 0, 0, 0);
    if (s < 15) { c0 = n0; c1 = n1; c2 = n2; c3 = n3; }
  }

  #pragma unroll
  for (int r = 0; r < 4; ++r) {
    int rowi = quad * 4 + r;
    red[w * 1088 + rowi * 68 + 0 + col] = acc0[r];
    red[w * 1088 + rowi * 68 + 16 + col] = acc1[r];
    red[w * 1088 + rowi * 68 + 32 + col] = acc2[r];
    red[w * 1088 + rowi * 68 + 48 + col] = acc3[r];
  }
  __syncthreads();

  int row = t >> 4, o4 = (t & 15) * 4;
  const float* rp = &red[row * 68 + o4];
  float4 s0 = *(const float4*)(rp);
  float4 s1 = *(const float4*)(rp + 1088);
  float4 s2 = *(const float4*)(rp + 2176);
  float4 s3 = *(const float4*)(rp + 3264);
  float4 o;
  o.x = fmaxf(s0.x + s1.x + s2.x + s3.x, 0.0f);
  o.y = fmaxf(s0.y + s1.y + s2.y + s3.y, 0.0f);
  o.z = fmaxf(s0.z + s1.z + s2.z + s3.z, 0.0f);
  o.w = fmaxf(s0.w + s1.w + s2.w + s3.w, 0.0f);
  *(float4*)&outp[(size_t)(b * NN + i0 + row) * FO + o4] = o;
}

// ---------------- K3b: fallback — recompute u from nt/f1/f2/bits -----------
__global__ __launch_bounds__(256) void k3_agg_b(
    const float* __restrict__ ntp,
    const unsigned char* __restrict__ bits,
    const float* __restrict__ f1,
    const float* __restrict__ f2,
    const unsigned short* __restrict__ vf,
    float* __restrict__ outp)
{
  __shared__ float red[4 * 16 * 68];
  int t = threadIdx.x;
  int b = blockIdx.x >> 7;
  int i0 = (blockIdx.x & 127) * 16;
  int w = t >> 6, l = t & 63;
  int col = l & 15, quad = l >> 4;
  int gi = b * NN + i0 + col;
  float f1v = f1[gi];
  const float* ntrow = ntp + (size_t)gi * NN;
  const unsigned char* brow = bits + (size_t)gi * (NN / 8);
  float4_t acc0 = {0, 0, 0, 0}, acc1 = {0, 0, 0, 0}, acc2 = {0, 0, 0, 0}, acc3 = {0, 0, 0, 0};

  for (int s = 0; s < 16; ++s) {
    int kk = w * 16 + s;
    int jq = kk * 32 + quad * 8;
    unsigned int m8 = brow[jq >> 3];
    float4 n0 = *(const float4*)(ntrow + jq);
    float4 n1 = *(const float4*)(ntrow + jq + 4);
    float4 g0 = *(const float4*)(f2 + b * NN + jq);
    float4 g1 = *(const float4*)(f2 + b * NN + jq + 4);
    float f2v[8] = {g0.x, g0.y, g0.z, g0.w, g1.x, g1.y, g1.z, g1.w};
    float ntf[8] = {n0.x, n0.y, n0.z, n0.w, n1.x, n1.y, n1.z, n1.w};
    union { unsigned int u[4]; short8_t v; } A;
    #pragma unroll
    for (int p = 0; p < 4; ++p) {
      int e0 = 2 * p, e1 = 2 * p + 1;
      float x0 = f1v + f2v[e0]; x0 = fmaxf(x0, 0.2f * x0);
      float u0 = ((m8 >> e0) & 1u) ? __expf(x0 * ntf[e0]) : 0.0f;
      float x1 = f1v + f2v[e1]; x1 = fmaxf(x1, 0.2f * x1);
      float u1 = ((m8 >> e1) & 1u) ? __expf(x1 * ntf[e1]) : 0.0f;
      A.u[p] = (unsigned int)f2bf(u0) | ((unsigned int)f2bf(u1) << 16);
    }
    const unsigned short* vb = vf + (size_t)(b * 64 + kk) * 2048 + l * 8;
    short8_t bf0 = *(const short8_t*)(vb);
    short8_t bf1 = *(const short8_t*)(vb + 512);
    short8_t bf2 = *(const short8_t*)(vb + 1024);
    short8_t bf3 = *(const short8_t*)(vb + 1536);
    acc0 = __builtin_amdgcn_mfma_f32_16x16x32_bf16(A.v, bf0, acc0, 0, 0, 0);
    acc1 = __builtin_amdgcn_mfma_f32_16x16x32_bf16(A.v, bf1, acc1, 0, 0, 0);
    acc2 = __builtin_amdgcn_mfma_f32_16x16x32_bf16(A.v, bf2, acc2, 0, 0, 0);
    acc3 = __builtin_amdgcn_mfma_f32_16x16x32_bf16(A.v, bf3, acc3, 0, 0, 0);
  }

  #pragma unroll
  for (int r = 0; r < 4; ++r) {
    int rowi = quad * 4 + r;
    red[w * 1088 + rowi * 68 + 0 + col] = acc0[r];
    red[w * 1088 + rowi * 68 + 16 + col] = acc1[r];
    red[w * 1088 + rowi * 68 + 32 + col] = acc2[r];
    red[w * 1088 + rowi * 68 + 48 + col] = acc3[r];
  }
  __syncthreads();

  int row = t >> 4, o4 = (t & 15) * 4;
  const float* rp = &red[row * 68 + o4];
  float4 s0 = *(const float4*)(rp);
  float4 s1 = *(const float4*)(rp + 1088);
  float4 s2 = *(const float4*)(rp + 2176);
  float4 s3 = *(const float4*)(rp + 3264);
  float4 o;
  o.x = fmaxf(s0.x + s1.x + s2.x + s3.x, 0.0f);
  o.y = fmaxf(s0.y + s1.y + s2.y + s3.y, 0.0f);
  o.z = fmaxf(s0.z + s1.z + s2.z + s3.z, 0.0f);
  o.w = fmaxf(s0.w + s1.w + s2.w + s3.w, 0.0f);
  *(float4*)&outp[(size_t)(b * NN + i0 + row) * FO + o4] = o;
}

extern "C" void kernel_launch(void* const* d_in, const int* in_sizes, int n_in,
                              void* d_out, int out_size, void* d_ws, size_t ws_size,
                              hipStream_t stream) {
  const float* h = (const float*)d_in[0];       // fp32 [B,N,FIN]
  const int* adj = (const int*)d_in[1];         // int32 [B,N,N]
  const float* level = (const float*)d_in[2];   // fp32 [B,N]
  const float* ntm = (const float*)d_in[3];     // fp32 [B,N,N]
  const float* W = (const float*)d_in[4];       // fp32 [FIN,FO]
  const float* a = (const float*)d_in[5];       // fp32 [2*FO,1]
  float* outp = (float*)d_out;

  float* V = (float*)d_ws;                              // 4 MB
  float* f1 = V + (size_t)BB * NN * FO;                 // 64 KB
  float* f2 = f1 + BB * NN;                             // 64 KB
  float* scol = f2 + BB * NN;                           // 64 KB
  unsigned short* vf = (unsigned short*)(scol + BB * NN); // 2 MB
  char* tail = (char*)(vf + (size_t)BB * NN * FO);
  size_t fixed = (size_t)(tail - (char*)d_ws);
  size_t need_u = fixed + (size_t)BB * NN * NN * 2;     // + 67 MB
  bool big = (ws_size >= need_u);

  k0_zero<<<64, 256, 0, stream>>>(scol);
  k1_gemm<<<1024, 256, 0, stream>>>(h, level, W, a, V, f1, f2);
  if (big) {
    unsigned short* u_bf = (unsigned short*)tail;
    k2a_stats<1><<<2048, 256, 0, stream>>>(adj, ntm, f1, f2, u_bf, nullptr, scol);
    k2b_pack<<<512, 256, 0, stream>>>(V, scol, vf);
    k3_agg_u<<<1024, 256, 0, stream>>>(u_bf, vf, outp);
  } else {
    unsigned char* bits = (unsigned char*)tail;         // + 4 MB
    k2a_stats<0><<<2048, 256, 0, stream>>>(adj, ntm, f1, f2, nullptr, bits, scol);
    k2b_pack<<<512, 256, 0, stream>>>(V, scol, vf);
    k3_agg_b<<<1024, 256, 0, stream>>>(ntm, bits, f1, f2, vf, outp);
  }
}

// Round 7
// 346.571 us; speedup vs baseline: 1.0959x; 1.0078x over previous
//
#include <hip/hip_runtime.h>

#define BB 8
#define NN 2048
#define FIN 256
#define FO 64

typedef short short8_t __attribute__((ext_vector_type(8)));
typedef float float4_t __attribute__((ext_vector_type(4)));

__device__ __forceinline__ unsigned short f2bf(float x) {
  unsigned int u = __float_as_uint(x);
  unsigned int r = (u + 0x7fffu + ((u >> 16) & 1u)) >> 16;
  return (unsigned short)r;
}

#define GLD16(gp, lp)                                                          \
  __builtin_amdgcn_global_load_lds(                                            \
      (const __attribute__((address_space(1))) void*)(gp),                     \
      (__attribute__((address_space(3))) void*)(lp), 16, 0, 0)

// ---------------- K1: Wh = h@W ; f1 ; f2 ; V = Wh*level ; zero scol ---------
__global__ __launch_bounds__(256) void k1_gemm(
    const float* __restrict__ h,
    const float* __restrict__ level,
    const float* __restrict__ W,
    const float* __restrict__ a,
    float* __restrict__ V, float* __restrict__ f1, float* __restrict__ f2,
    float* __restrict__ scol)
{
  __shared__ float wlds[128 * 64];
  __shared__ float hs[16 * 260];
  __shared__ float parts1[16 * 17];
  __shared__ float parts2[16 * 17];
  int t = threadIdx.x;
  int b = blockIdx.x >> 7;
  int i0 = (blockIdx.x & 127) * 16;

  if (blockIdx.x < 64) scol[blockIdx.x * 256 + t] = 0.0f;  // folded k0

  {
    int r_ld = t >> 4, f0 = (t & 15) * 16;
    const float* hp = h + (size_t)(b * NN + i0 + r_ld) * FIN + f0;
    float4 x0 = *(const float4*)(hp);
    float4 x1 = *(const float4*)(hp + 4);
    float4 x2 = *(const float4*)(hp + 8);
    float4 x3 = *(const float4*)(hp + 12);
    float* hd = &hs[r_ld * 260 + f0];
    *(float4*)(hd + 0) = x0; *(float4*)(hd + 4) = x1;
    *(float4*)(hd + 8) = x2; *(float4*)(hd + 12) = x3;
  }

  int r = t >> 4;
  int c4 = (t & 15) * 4;
  float4 acc = {0, 0, 0, 0};

  #pragma unroll
  for (int half = 0; half < 2; ++half) {
    __syncthreads();
    #pragma unroll
    for (int q = 0; q < 8; ++q) {
      int idx = q * 1024 + t * 4;
      *(float4*)&wlds[idx] = *(const float4*)&W[half * 8192 + idx];
    }
    __syncthreads();
    for (int f = 0; f < 128; f += 8) {
      float4 hv0 = *(const float4*)&hs[r * 260 + half * 128 + f];
      float4 hv1 = *(const float4*)&hs[r * 260 + half * 128 + f + 4];
      float hvv[8] = {hv0.x, hv0.y, hv0.z, hv0.w, hv1.x, hv1.y, hv1.z, hv1.w};
      #pragma unroll
      for (int k = 0; k < 8; ++k) {
        float4 wv = *(const float4*)&wlds[(f + k) * 64 + c4];
        acc.x += hvv[k] * wv.x; acc.y += hvv[k] * wv.y;
        acc.z += hvv[k] * wv.z; acc.w += hvv[k] * wv.w;
      }
    }
  }

  float p1 = acc.x * a[c4] + acc.y * a[c4 + 1] + acc.z * a[c4 + 2] + acc.w * a[c4 + 3];
  float p2 = acc.x * a[64 + c4] + acc.y * a[64 + c4 + 1] +
             acc.z * a[64 + c4 + 2] + acc.w * a[64 + c4 + 3];
  parts1[r * 17 + (t & 15)] = p1;
  parts2[r * 17 + (t & 15)] = p2;
  __syncthreads();
  if (t < 16) {
    float s1 = 0.f, s2 = 0.f;
    #pragma unroll
    for (int g = 0; g < 16; ++g) { s1 += parts1[t * 17 + g]; s2 += parts2[t * 17 + g]; }
    f1[b * NN + i0 + t] = s1;
    f2[b * NN + i0 + t] = s2;
  }

  float lv = level[b * NN + i0 + r];
  float4 vv = {acc.x * lv, acc.y * lv, acc.z * lv, acc.w * lv};
  *(float4*)&V[(size_t)(b * NN + i0 + r) * FO + c4] = vv;
}

// ---------------- K2a: column sums + u (blocked A-frag layout) --------------
// grid 512 (8 b x 64 32-row spans), 512 threads (8 waves), 2 blocks/CU.
// Tiles: 2 x (16 rows) x 8 chunks of 256 cols. DMA prefetch issued BEFORE
// compute (true overlap). Thread t owns column j = c*256 + (t&255) for its
// 8 rows -> per-chunk register accumulators, one reduce at block end.
// STORE_U=1 writes u in MFMA-A fragment-blocked order:
//   u_frag[((b*128+it)*64+kk)*512 + (quad*16+m)*8 + e],  m=i&15, k=quad*8+e.
template <int STORE_U>
__global__ __launch_bounds__(512) void k2a_stats(
    const int* __restrict__ adj,
    const float* __restrict__ ntp,
    const float* __restrict__ f1,
    const float* __restrict__ f2,
    unsigned short* __restrict__ u_bf,
    unsigned char* __restrict__ bits,
    float* __restrict__ scol)
{
  __shared__ int ladj[2][16 * 256];   // 32 KB
  __shared__ float lnt[2][16 * 256];  // 32 KB
  __shared__ float red[2048];         // 8 KB
  int t = threadIdx.x;
  int b = blockIdx.x >> 6;
  int row0 = (blockIdx.x & 63) * 32;
  int w = t >> 6, l = t & 63;
  size_t base = (size_t)b * NN;

  auto stage = [&](int buf, int s) {
    int tile = s >> 3, c = s & 7;
    int r0 = row0 + tile * 16 + 2 * w;   // wave w stages tile-rows 2w, 2w+1
    const int* ga = adj + (base + r0) * NN + c * 256 + l * 4;
    const float* gn = ntp + (base + r0) * NN + c * 256 + l * 4;
    GLD16(ga, &ladj[buf][(2 * w) * 256]);
    GLD16(ga + NN, &ladj[buf][(2 * w + 1) * 256]);
    GLD16(gn, &lnt[buf][(2 * w) * 256]);
    GLD16(gn + NN, &lnt[buf][(2 * w + 1) * 256]);
  };

  int jj = t & 255;       // column within chunk
  int rh = t >> 8;        // 0: tile rows 0-7, 1: rows 8-15
  int kk_in = jj >> 5;    // kk within chunk (0..7)
  int quad = (jj & 31) >> 3;
  int e = jj & 7;

  float accJ[8];
  #pragma unroll
  for (int c = 0; c < 8; ++c) accJ[c] = 0.f;
  float f2v[8];
  #pragma unroll
  for (int c = 0; c < 8; ++c) f2v[c] = f2[base + c * 256 + jj];

  stage(0, 0);
  for (int s = 0; s < 16; ++s) {
    int buf = s & 1;
    __syncthreads();                     // staged(s) ready; buf^1 free
    if (s < 15) stage(buf ^ 1, s + 1);   // prefetch overlaps compute below
    int tile = s >> 3, c = s & 7;
    int it = (row0 >> 4) + tile;
    size_t fbase = ((size_t)(b * 128 + it) * 64 + (c * 8 + kk_in)) * 512
                   + quad * 128 + rh * 64 + e;
    #pragma unroll
    for (int q = 0; q < 8; ++q) {
      int r = rh * 8 + q;                // row within tile
      int av = ladj[buf][r * 256 + jj];
      float nv = lnt[buf][r * 256 + jj];
      float f1v = f1[base + row0 + tile * 16 + r];
      float x = f1v + f2v[c];
      x = fmaxf(x, 0.2f * x);            // leaky_relu slope 0.2
      bool m = av > 0;
      float u = m ? __expf(x * nv) : 0.0f;
      accJ[c] += u;
      if (STORE_U) {
        u_bf[fbase + q * 8] = f2bf(u);
      } else {
        unsigned long long bal = __ballot(m);
        if (l == 0)
          *(unsigned long long*)&bits[(base + row0 + tile * 16 + r) * (NN / 8)
                                      + c * 32 + (w & 3) * 8] = bal;
      }
    }
  }

  // column-sum combine: rh=0 writes, rh=1 adds, then 4 atomics/thread
  if (rh == 0) {
    #pragma unroll
    for (int c = 0; c < 8; ++c) red[c * 256 + jj] = accJ[c];
  }
  __syncthreads();
  if (rh == 1) {
    #pragma unroll
    for (int c = 0; c < 8; ++c) red[c * 256 + jj] += accJ[c];
  }
  __syncthreads();
  #pragma unroll
  for (int q = 0; q < 4; ++q)
    atomicAdd(&scol[base + q * 512 + t], red[q * 512 + t]);
}

// ---------------- K2b: pack V'[j][o]=V[j][o]/s_j into MFMA B-frag order -----
__global__ __launch_bounds__(256) void k2b_pack(
    const float* __restrict__ V,
    const float* __restrict__ scol,
    unsigned short* __restrict__ vf)
{
  int t = threadIdx.x;
  int b = blockIdx.x >> 6;
  int kk = blockIdx.x & 63;
  int ng = t >> 6;
  int l = t & 63;
  int jb = kk * 32 + ((l >> 4) * 8);
  int o = ng * 16 + (l & 15);
  unsigned int pk[4];
  #pragma unroll
  for (int p = 0; p < 4; ++p) {
    int jr0 = jb + 2 * p, jr1 = jb + 2 * p + 1;
    float s0 = scol[b * NN + jr0];
    float s1 = scol[b * NN + jr1];
    float i0 = (s0 > 0.f) ? (1.0f / s0) : 0.0f;
    float i1 = (s1 > 0.f) ? (1.0f / s1) : 0.0f;
    float v0 = V[(size_t)(b * NN + jr0) * FO + o] * i0;
    float v1 = V[(size_t)(b * NN + jr1) * FO + o] * i1;
    pk[p] = (unsigned int)f2bf(v0) | ((unsigned int)f2bf(v1) << 16);
  }
  *(uint4*)(vf + (size_t)(((b * 64 + kk) * 4 + ng) * 64 + l) * 8) =
      make_uint4(pk[0], pk[1], pk[2], pk[3]);
}

// ---------------- K3a: out = relu(U @ V'), U in blocked A-frag layout -------
__global__ __launch_bounds__(256) void k3_agg_u(
    const unsigned short* __restrict__ u_bf,
    const unsigned short* __restrict__ vf,
    float* __restrict__ outp)
{
  __shared__ float red[4 * 16 * 68];
  int t = threadIdx.x;
  int b = blockIdx.x >> 7;
  int it = blockIdx.x & 127;
  int i0 = it * 16;
  int w = t >> 6, l = t & 63;
  int col = l & 15, quad = l >> 4;
  const unsigned short* abase = u_bf + ((size_t)(b * 128 + it) * 64) * 512 + l * 8;
  const unsigned short* vbase = vf + (size_t)(b * 64) * 2048 + l * 8;

  short8_t Aall[16];
  #pragma unroll
  for (int s = 0; s < 16; ++s)
    Aall[s] = *(const short8_t*)(abase + (size_t)(w * 16 + s) * 512);

  const unsigned short* vb0 = vbase + (size_t)(w * 16) * 2048;
  short8_t c0 = *(const short8_t*)(vb0);
  short8_t c1 = *(const short8_t*)(vb0 + 512);
  short8_t c2 = *(const short8_t*)(vb0 + 1024);
  short8_t c3 = *(const short8_t*)(vb0 + 1536);

  float4_t acc0 = {0, 0, 0, 0}, acc1 = {0, 0, 0, 0}, acc2 = {0, 0, 0, 0}, acc3 = {0, 0, 0, 0};

  #pragma unroll
  for (int s = 0; s < 16; ++s) {
    short8_t n0, n1, n2, n3;
    if (s < 15) {
      const unsigned short* vn = vbase + (size_t)(w * 16 + s + 1) * 2048;
      n0 = *(const short8_t*)(vn);
      n1 = *(const short8_t*)(vn + 512);
      n2 = *(const short8_t*)(vn + 1024);
      n3 = *(const short8_t*)(vn + 1536);
    }
    acc0 = __builtin_amdgcn_mfma_f32_16x16x32_bf16(Aall[s], c0, acc0, 0, 0, 0);
    acc1 = __builtin_amdgcn_mfma_f32_16x16x32_bf16(Aall[s], c1, acc1, 0, 0, 0);
    acc2 = __builtin_amdgcn_mfma_f32_16x16x32_bf16(Aall[s], c2, acc2, 0, 0, 0);
    acc3 = __builtin_amdgcn_mfma_f32_16x16x32_bf16(Aall[s], c3, acc3, 0, 0, 0);
    if (s < 15) { c0 = n0; c1 = n1; c2 = n2; c3 = n3; }
  }

  #pragma unroll
  for (int r = 0; r < 4; ++r) {
    int rowi = quad * 4 + r;
    red[w * 1088 + rowi * 68 + 0 + col] = acc0[r];
    red[w * 1088 + rowi * 68 + 16 + col] = acc1[r];
    red[w * 1088 + rowi * 68 + 32 + col] = acc2[r];
    red[w * 1088 + rowi * 68 + 48 + col] = acc3[r];
  }
  __syncthreads();

  int row = t >> 4, o4 = (t & 15) * 4;
  const float* rp = &red[row * 68 + o4];
  float4 s0 = *(const float4*)(rp);
  float4 s1 = *(const float4*)(rp + 1088);
  float4 s2 = *(const float4*)(rp + 2176);
  float4 s3 = *(const float4*)(rp + 3264);
  float4 o;
  o.x = fmaxf(s0.x + s1.x + s2.x + s3.x, 0.0f);
  o.y = fmaxf(s0.y + s1.y + s2.y + s3.y, 0.0f);
  o.z = fmaxf(s0.z + s1.z + s2.z + s3.z, 0.0f);
  o.w = fmaxf(s0.w + s1.w + s2.w + s3.w, 0.0f);
  *(float4*)&outp[(size_t)(b * NN + i0 + row) * FO + o4] = o;
}

// ---------------- K3b: fallback — recompute u from nt/f1/f2/bits -----------
__global__ __launch_bounds__(256) void k3_agg_b(
    const float* __restrict__ ntp,
    const unsigned char* __restrict__ bits,
    const float* __restrict__ f1,
    const float* __restrict__ f2,
    const unsigned short* __restrict__ vf,
    float* __restrict__ outp)
{
  __shared__ float red[4 * 16 * 68];
  int t = threadIdx.x;
  int b = blockIdx.x >> 7;
  int i0 = (blockIdx.x & 127) * 16;
  int w = t >> 6, l = t & 63;
  int col = l & 15, quad = l >> 4;
  int gi = b * NN + i0 + col;
  float f1v = f1[gi];
  const float* ntrow = ntp + (size_t)gi * NN;
  const unsigned char* brow = bits + (size_t)gi * (NN / 8);
  float4_t acc0 = {0, 0, 0, 0}, acc1 = {0, 0, 0, 0}, acc2 = {0, 0, 0, 0}, acc3 = {0, 0, 0, 0};

  for (int s = 0; s < 16; ++s) {
    int kk = w * 16 + s;
    int jq = kk * 32 + quad * 8;
    unsigned int m8 = brow[jq >> 3];
    float4 n0 = *(const float4*)(ntrow + jq);
    float4 n1 = *(const float4*)(ntrow + jq + 4);
    float4 g0 = *(const float4*)(f2 + b * NN + jq);
    float4 g1 = *(const float4*)(f2 + b * NN + jq + 4);
    float f2v[8] = {g0.x, g0.y, g0.z, g0.w, g1.x, g1.y, g1.z, g1.w};
    float ntf[8] = {n0.x, n0.y, n0.z, n0.w, n1.x, n1.y, n1.z, n1.w};
    union { unsigned int u[4]; short8_t v; } A;
    #pragma unroll
    for (int p = 0; p < 4; ++p) {
      int e0 = 2 * p, e1 = 2 * p + 1;
      float x0 = f1v + f2v[e0]; x0 = fmaxf(x0, 0.2f * x0);
      float u0 = ((m8 >> e0) & 1u) ? __expf(x0 * ntf[e0]) : 0.0f;
      float x1 = f1v + f2v[e1]; x1 = fmaxf(x1, 0.2f * x1);
      float u1 = ((m8 >> e1) & 1u) ? __expf(x1 * ntf[e1]) : 0.0f;
      A.u[p] = (unsigned int)f2bf(u0) | ((unsigned int)f2bf(u1) << 16);
    }
    const unsigned short* vb = vf + (size_t)(b * 64 + kk) * 2048 + l * 8;
    short8_t bf0 = *(const short8_t*)(vb);
    short8_t bf1 = *(const short8_t*)(vb + 512);
    short8_t bf2 = *(const short8_t*)(vb + 1024);
    short8_t bf3 = *(const short8_t*)(vb + 1536);
    acc0 = __builtin_amdgcn_mfma_f32_16x16x32_bf16(A.v, bf0, acc0, 0, 0, 0);
    acc1 = __builtin_amdgcn_mfma_f32_16x16x32_bf16(A.v, bf1, acc1, 0, 0, 0);
    acc2 = __builtin_amdgcn_mfma_f32_16x16x32_bf16(A.v, bf2, acc2, 0, 0, 0);
    acc3 = __builtin_amdgcn_mfma_f32_16x16x32_bf16(A.v, bf3, acc3, 0, 0, 0);
  }

  #pragma unroll
  for (int r = 0; r < 4; ++r) {
    int rowi = quad * 4 + r;
    red[w * 1088 + rowi * 68 + 0 + col] = acc0[r];
    red[w * 1088 + rowi * 68 + 16 + col] = acc1[r];
    red[w * 1088 + rowi * 68 + 32 + col] = acc2[r];
    red[w * 1088 + rowi * 68 + 48 + col] = acc3[r];
  }
  __syncthreads();

  int row = t >> 4, o4 = (t & 15) * 4;
  const float* rp = &red[row * 68 + o4];
  float4 s0 = *(const float4*)(rp);
  float4 s1 = *(const float4*)(rp + 1088);
  float4 s2 = *(const float4*)(rp + 2176);
  float4 s3 = *(const float4*)(rp + 3264);
  float4 o;
  o.x = fmaxf(s0.x + s1.x + s2.x + s3.x, 0.0f);
  o.y = fmaxf(s0.y + s1.y + s2.y + s3.y, 0.0f);
  o.z = fmaxf(s0.z + s1.z + s2.z + s3.z, 0.0f);
  o.w = fmaxf(s0.w + s1.w + s2.w + s3.w, 0.0f);
  *(float4*)&outp[(size_t)(b * NN + i0 + row) * FO + o4] = o;
}

extern "C" void kernel_launch(void* const* d_in, const int* in_sizes, int n_in,
                              void* d_out, int out_size, void* d_ws, size_t ws_size,
                              hipStream_t stream) {
  const float* h = (const float*)d_in[0];       // fp32 [B,N,FIN]
  const int* adj = (const int*)d_in[1];         // int32 [B,N,N]
  const float* level = (const float*)d_in[2];   // fp32 [B,N]
  const float* ntm = (const float*)d_in[3];     // fp32 [B,N,N]
  const float* W = (const float*)d_in[4];       // fp32 [FIN,FO]
  const float* a = (const float*)d_in[5];       // fp32 [2*FO,1]
  float* outp = (float*)d_out;

  float* V = (float*)d_ws;                              // 4 MB
  float* f1 = V + (size_t)BB * NN * FO;                 // 64 KB
  float* f2 = f1 + BB * NN;                             // 64 KB
  float* scol = f2 + BB * NN;                           // 64 KB
  unsigned short* vf = (unsigned short*)(scol + BB * NN); // 2 MB
  char* tail = (char*)(vf + (size_t)BB * NN * FO);
  size_t fixed = (size_t)(tail - (char*)d_ws);
  size_t need_u = fixed + (size_t)BB * NN * NN * 2;     // + 67 MB
  bool big = (ws_size >= need_u);

  k1_gemm<<<1024, 256, 0, stream>>>(h, level, W, a, V, f1, f2, scol);
  if (big) {
    unsigned short* u_bf = (unsigned short*)tail;
    k2a_stats<1><<<512, 512, 0, stream>>>(adj, ntm, f1, f2, u_bf, nullptr, scol);
    k2b_pack<<<512, 256, 0, stream>>>(V, scol, vf);
    k3_agg_u<<<1024, 256, 0, stream>>>(u_bf, vf, outp);
  } else {
    unsigned char* bits = (unsigned char*)tail;         // + 4 MB
    k2a_stats<0><<<512, 512, 0, stream>>>(adj, ntm, f1, f2, nullptr, bits, scol);
    k2b_pack<<<512, 256, 0, stream>>>(V, scol, vf);
    k3_agg_b<<<1024, 256, 0, stream>>>(ntm, bits, f1, f2, vf, outp);
  }
}

// Round 8
// 341.057 us; speedup vs baseline: 1.1136x; 1.0162x over previous
//
#include <hip/hip_runtime.h>

#define BB 8
#define NN 2048
#define FIN 256
#define FO 64

typedef short short8_t __attribute__((ext_vector_type(8)));
typedef float float4_t __attribute__((ext_vector_type(4)));

__device__ __forceinline__ unsigned short f2bf(float x) {
  unsigned int u = __float_as_uint(x);
  unsigned int r = (u + 0x7fffu + ((u >> 16) & 1u)) >> 16;
  return (unsigned short)r;
}

#define GLD16(gp, lp)                                                          \
  __builtin_amdgcn_global_load_lds(                                            \
      (const __attribute__((address_space(1))) void*)(gp),                     \
      (__attribute__((address_space(3))) void*)(lp), 16, 0, 0)

// ---------------- K1: Wh = h@W ; f1 ; f2 ; V = Wh*level ; zero scol ---------
__global__ __launch_bounds__(256) void k1_gemm(
    const float* __restrict__ h,
    const float* __restrict__ level,
    const float* __restrict__ W,
    const float* __restrict__ a,
    float* __restrict__ V, float* __restrict__ f1, float* __restrict__ f2,
    float* __restrict__ scol)
{
  __shared__ float wlds[128 * 64];
  __shared__ float hs[16 * 260];
  __shared__ float parts1[16 * 17];
  __shared__ float parts2[16 * 17];
  int t = threadIdx.x;
  int b = blockIdx.x >> 7;
  int i0 = (blockIdx.x & 127) * 16;

  if (blockIdx.x < 64) scol[blockIdx.x * 256 + t] = 0.0f;  // folded k0

  {
    int r_ld = t >> 4, f0 = (t & 15) * 16;
    const float* hp = h + (size_t)(b * NN + i0 + r_ld) * FIN + f0;
    float4 x0 = *(const float4*)(hp);
    float4 x1 = *(const float4*)(hp + 4);
    float4 x2 = *(const float4*)(hp + 8);
    float4 x3 = *(const float4*)(hp + 12);
    float* hd = &hs[r_ld * 260 + f0];
    *(float4*)(hd + 0) = x0; *(float4*)(hd + 4) = x1;
    *(float4*)(hd + 8) = x2; *(float4*)(hd + 12) = x3;
  }

  int r = t >> 4;
  int c4 = (t & 15) * 4;
  float4 acc = {0, 0, 0, 0};

  #pragma unroll
  for (int half = 0; half < 2; ++half) {
    __syncthreads();
    #pragma unroll
    for (int q = 0; q < 8; ++q) {
      int idx = q * 1024 + t * 4;
      *(float4*)&wlds[idx] = *(const float4*)&W[half * 8192 + idx];
    }
    __syncthreads();
    for (int f = 0; f < 128; f += 8) {
      float4 hv0 = *(const float4*)&hs[r * 260 + half * 128 + f];
      float4 hv1 = *(const float4*)&hs[r * 260 + half * 128 + f + 4];
      float hvv[8] = {hv0.x, hv0.y, hv0.z, hv0.w, hv1.x, hv1.y, hv1.z, hv1.w};
      #pragma unroll
      for (int k = 0; k < 8; ++k) {
        float4 wv = *(const float4*)&wlds[(f + k) * 64 + c4];
        acc.x += hvv[k] * wv.x; acc.y += hvv[k] * wv.y;
        acc.z += hvv[k] * wv.z; acc.w += hvv[k] * wv.w;
      }
    }
  }

  float p1 = acc.x * a[c4] + acc.y * a[c4 + 1] + acc.z * a[c4 + 2] + acc.w * a[c4 + 3];
  float p2 = acc.x * a[64 + c4] + acc.y * a[64 + c4 + 1] +
             acc.z * a[64 + c4 + 2] + acc.w * a[64 + c4 + 3];
  parts1[r * 17 + (t & 15)] = p1;
  parts2[r * 17 + (t & 15)] = p2;
  __syncthreads();
  if (t < 16) {
    float s1 = 0.f, s2 = 0.f;
    #pragma unroll
    for (int g = 0; g < 16; ++g) { s1 += parts1[t * 17 + g]; s2 += parts2[t * 17 + g]; }
    f1[b * NN + i0 + t] = s1;
    f2[b * NN + i0 + t] = s2;
  }

  float lv = level[b * NN + i0 + r];
  float4 vv = {acc.x * lv, acc.y * lv, acc.z * lv, acc.w * lv};
  *(float4*)&V[(size_t)(b * NN + i0 + r) * FO + c4] = vv;
}

// ---------------- K2a: column sums + u (blocked A-frag layout) --------------
// (unchanged from round 7 — at its ~3.1 TB/s L2-side wall)
template <int STORE_U>
__global__ __launch_bounds__(512) void k2a_stats(
    const int* __restrict__ adj,
    const float* __restrict__ ntp,
    const float* __restrict__ f1,
    const float* __restrict__ f2,
    unsigned short* __restrict__ u_bf,
    unsigned char* __restrict__ bits,
    float* __restrict__ scol)
{
  __shared__ int ladj[2][16 * 256];   // 32 KB
  __shared__ float lnt[2][16 * 256];  // 32 KB
  __shared__ float red[2048];         // 8 KB
  int t = threadIdx.x;
  int b = blockIdx.x >> 6;
  int row0 = (blockIdx.x & 63) * 32;
  int w = t >> 6, l = t & 63;
  size_t base = (size_t)b * NN;

  auto stage = [&](int buf, int s) {
    int tile = s >> 3, c = s & 7;
    int r0 = row0 + tile * 16 + 2 * w;
    const int* ga = adj + (base + r0) * NN + c * 256 + l * 4;
    const float* gn = ntp + (base + r0) * NN + c * 256 + l * 4;
    GLD16(ga, &ladj[buf][(2 * w) * 256]);
    GLD16(ga + NN, &ladj[buf][(2 * w + 1) * 256]);
    GLD16(gn, &lnt[buf][(2 * w) * 256]);
    GLD16(gn + NN, &lnt[buf][(2 * w + 1) * 256]);
  };

  int jj = t & 255;
  int rh = t >> 8;
  int kk_in = jj >> 5;
  int quad = (jj & 31) >> 3;
  int e = jj & 7;

  float accJ[8];
  #pragma unroll
  for (int c = 0; c < 8; ++c) accJ[c] = 0.f;
  float f2v[8];
  #pragma unroll
  for (int c = 0; c < 8; ++c) f2v[c] = f2[base + c * 256 + jj];

  stage(0, 0);
  for (int s = 0; s < 16; ++s) {
    int buf = s & 1;
    __syncthreads();
    if (s < 15) stage(buf ^ 1, s + 1);
    int tile = s >> 3, c = s & 7;
    int it = (row0 >> 4) + tile;
    size_t fbase = ((size_t)(b * 128 + it) * 64 + (c * 8 + kk_in)) * 512
                   + quad * 128 + rh * 64 + e;
    #pragma unroll
    for (int q = 0; q < 8; ++q) {
      int r = rh * 8 + q;
      int av = ladj[buf][r * 256 + jj];
      float nv = lnt[buf][r * 256 + jj];
      float f1v = f1[base + row0 + tile * 16 + r];
      float x = f1v + f2v[c];
      x = fmaxf(x, 0.2f * x);            // leaky_relu slope 0.2
      bool m = av > 0;
      float u = m ? __expf(x * nv) : 0.0f;
      accJ[c] += u;
      if (STORE_U) {
        u_bf[fbase + q * 8] = f2bf(u);
      } else {
        unsigned long long bal = __ballot(m);
        if (l == 0)
          *(unsigned long long*)&bits[(base + row0 + tile * 16 + r) * (NN / 8)
                                      + c * 32 + (w & 3) * 8] = bal;
      }
    }
  }

  if (rh == 0) {
    #pragma unroll
    for (int c = 0; c < 8; ++c) red[c * 256 + jj] = accJ[c];
  }
  __syncthreads();
  if (rh == 1) {
    #pragma unroll
    for (int c = 0; c < 8; ++c) red[c * 256 + jj] += accJ[c];
  }
  __syncthreads();
  #pragma unroll
  for (int q = 0; q < 4; ++q)
    atomicAdd(&scol[base + q * 512 + t], red[q * 512 + t]);
}

// ---------------- K2b: pack V'[j][o]=V[j][o]/s_j into MFMA B-frag order -----
__global__ __launch_bounds__(256) void k2b_pack(
    const float* __restrict__ V,
    const float* __restrict__ scol,
    unsigned short* __restrict__ vf)
{
  int t = threadIdx.x;
  int b = blockIdx.x >> 6;
  int kk = blockIdx.x & 63;
  int ng = t >> 6;
  int l = t & 63;
  int jb = kk * 32 + ((l >> 4) * 8);
  int o = ng * 16 + (l & 15);
  unsigned int pk[4];
  #pragma unroll
  for (int p = 0; p < 4; ++p) {
    int jr0 = jb + 2 * p, jr1 = jb + 2 * p + 1;
    float s0 = scol[b * NN + jr0];
    float s1 = scol[b * NN + jr1];
    float i0 = (s0 > 0.f) ? (1.0f / s0) : 0.0f;
    float i1 = (s1 > 0.f) ? (1.0f / s1) : 0.0f;
    float v0 = V[(size_t)(b * NN + jr0) * FO + o] * i0;
    float v1 = V[(size_t)(b * NN + jr1) * FO + o] * i1;
    pk[p] = (unsigned int)f2bf(v0) | ((unsigned int)f2bf(v1) << 16);
  }
  *(uint4*)(vf + (size_t)(((b * 64 + kk) * 4 + ng) * 64 + l) * 8) =
      make_uint4(pk[0], pk[1], pk[2], pk[3]);
}

// ---------------- K3: out = relu(U @ V'), 64-row i-tiles --------------------
// grid 256 (8 b x 32 tiles of 64 rows), 512 threads = 8 waves. Wave w owns
// kk = w*8..w*8+7; 4 sub-tiles of 16 rows share each vf fragment load
// (vf L2 traffic 262 -> 65 MB). Cross-wave k-reduce in LDS per sub-tile.
__global__ __launch_bounds__(512) void k3_agg_u2(
    const unsigned short* __restrict__ u_bf,
    const unsigned short* __restrict__ vf,
    float* __restrict__ outp)
{
  __shared__ float red[8 * 16 * 68];   // 34.8 KB
  int t = threadIdx.x;
  int b = blockIdx.x >> 5;
  int tt = blockIdx.x & 31;
  int w = t >> 6, l = t & 63;
  int col = l & 15, quad = l >> 4;
  const unsigned short* vbase = vf + (size_t)(b * 64) * 2048 + l * 8;
  const unsigned short* abase =
      u_bf + ((size_t)(b * 128 + tt * 4) * 64) * 512 + l * 8;

  float4_t acc[4][4];  // [sub][ng]
  #pragma unroll
  for (int s = 0; s < 4; ++s)
    #pragma unroll
    for (int g = 0; g < 4; ++g) acc[s][g] = (float4_t){0, 0, 0, 0};

  for (int s = 0; s < 8; ++s) {
    int kk = w * 8 + s;
    const unsigned short* vb = vbase + (size_t)kk * 2048;
    short8_t c0 = *(const short8_t*)(vb);
    short8_t c1 = *(const short8_t*)(vb + 512);
    short8_t c2 = *(const short8_t*)(vb + 1024);
    short8_t c3 = *(const short8_t*)(vb + 1536);
    const unsigned short* ab = abase + (size_t)kk * 512;
    short8_t A0 = *(const short8_t*)(ab);
    short8_t A1 = *(const short8_t*)(ab + 64 * 512);
    short8_t A2 = *(const short8_t*)(ab + 128 * 512);
    short8_t A3 = *(const short8_t*)(ab + 192 * 512);
    acc[0][0] = __builtin_amdgcn_mfma_f32_16x16x32_bf16(A0, c0, acc[0][0], 0, 0, 0);
    acc[0][1] = __builtin_amdgcn_mfma_f32_16x16x32_bf16(A0, c1, acc[0][1], 0, 0, 0);
    acc[0][2] = __builtin_amdgcn_mfma_f32_16x16x32_bf16(A0, c2, acc[0][2], 0, 0, 0);
    acc[0][3] = __builtin_amdgcn_mfma_f32_16x16x32_bf16(A0, c3, acc[0][3], 0, 0, 0);
    acc[1][0] = __builtin_amdgcn_mfma_f32_16x16x32_bf16(A1, c0, acc[1][0], 0, 0, 0);
    acc[1][1] = __builtin_amdgcn_mfma_f32_16x16x32_bf16(A1, c1, acc[1][1], 0, 0, 0);
    acc[1][2] = __builtin_amdgcn_mfma_f32_16x16x32_bf16(A1, c2, acc[1][2], 0, 0, 0);
    acc[1][3] = __builtin_amdgcn_mfma_f32_16x16x32_bf16(A1, c3, acc[1][3], 0, 0, 0);
    acc[2][0] = __builtin_amdgcn_mfma_f32_16x16x32_bf16(A2, c0, acc[2][0], 0, 0, 0);
    acc[2][1] = __builtin_amdgcn_mfma_f32_16x16x32_bf16(A2, c1, acc[2][1], 0, 0, 0);
    acc[2][2] = __builtin_amdgcn_mfma_f32_16x16x32_bf16(A2, c2, acc[2][2], 0, 0, 0);
    acc[2][3] = __builtin_amdgcn_mfma_f32_16x16x32_bf16(A2, c3, acc[2][3], 0, 0, 0);
    acc[3][0] = __builtin_amdgcn_mfma_f32_16x16x32_bf16(A3, c0, acc[3][0], 0, 0, 0);
    acc[3][1] = __builtin_amdgcn_mfma_f32_16x16x32_bf16(A3, c1, acc[3][1], 0, 0, 0);
    acc[3][2] = __builtin_amdgcn_mfma_f32_16x16x32_bf16(A3, c2, acc[3][2], 0, 0, 0);
    acc[3][3] = __builtin_amdgcn_mfma_f32_16x16x32_bf16(A3, c3, acc[3][3], 0, 0, 0);
  }

  for (int sub = 0; sub < 4; ++sub) {
    __syncthreads();  // red free (first iter: trivially)
    #pragma unroll
    for (int r = 0; r < 4; ++r) {
      int rowi = quad * 4 + r;
      float* rp = &red[w * 1088 + rowi * 68 + col];
      rp[0] = acc[sub][0][r];
      rp[16] = acc[sub][1][r];
      rp[32] = acc[sub][2][r];
      rp[48] = acc[sub][3][r];
    }
    __syncthreads();
    if (t < 256) {
      int row = t >> 4, o4 = (t & 15) * 4;
      const float* rp = &red[row * 68 + o4];
      float4 s0 = *(const float4*)(rp);
      float4 s1 = *(const float4*)(rp + 1088);
      float4 s2 = *(const float4*)(rp + 2176);
      float4 s3 = *(const float4*)(rp + 3264);
      float4 s4 = *(const float4*)(rp + 4352);
      float4 s5 = *(const float4*)(rp + 5440);
      float4 s6 = *(const float4*)(rp + 6528);
      float4 s7 = *(const float4*)(rp + 7616);
      float4 o;
      o.x = fmaxf(s0.x + s1.x + s2.x + s3.x + s4.x + s5.x + s6.x + s7.x, 0.0f);
      o.y = fmaxf(s0.y + s1.y + s2.y + s3.y + s4.y + s5.y + s6.y + s7.y, 0.0f);
      o.z = fmaxf(s0.z + s1.z + s2.z + s3.z + s4.z + s5.z + s6.z + s7.z, 0.0f);
      o.w = fmaxf(s0.w + s1.w + s2.w + s3.w + s4.w + s5.w + s6.w + s7.w, 0.0f);
      *(float4*)&outp[(size_t)(b * NN + tt * 64 + sub * 16 + row) * FO + o4] = o;
    }
  }
}

// ---------------- K3b: fallback — recompute u from nt/f1/f2/bits -----------
__global__ __launch_bounds__(256) void k3_agg_b(
    const float* __restrict__ ntp,
    const unsigned char* __restrict__ bits,
    const float* __restrict__ f1,
    const float* __restrict__ f2,
    const unsigned short* __restrict__ vf,
    float* __restrict__ outp)
{
  __shared__ float red[4 * 16 * 68];
  int t = threadIdx.x;
  int b = blockIdx.x >> 7;
  int i0 = (blockIdx.x & 127) * 16;
  int w = t >> 6, l = t & 63;
  int col = l & 15, quad = l >> 4;
  int gi = b * NN + i0 + col;
  float f1v = f1[gi];
  const float* ntrow = ntp + (size_t)gi * NN;
  const unsigned char* brow = bits + (size_t)gi * (NN / 8);
  float4_t acc0 = {0, 0, 0, 0}, acc1 = {0, 0, 0, 0}, acc2 = {0, 0, 0, 0}, acc3 = {0, 0, 0, 0};

  for (int s = 0; s < 16; ++s) {
    int kk = w * 16 + s;
    int jq = kk * 32 + quad * 8;
    unsigned int m8 = brow[jq >> 3];
    float4 n0 = *(const float4*)(ntrow + jq);
    float4 n1 = *(const float4*)(ntrow + jq + 4);
    float4 g0 = *(const float4*)(f2 + b * NN + jq);
    float4 g1 = *(const float4*)(f2 + b * NN + jq + 4);
    float f2v[8] = {g0.x, g0.y, g0.z, g0.w, g1.x, g1.y, g1.z, g1.w};
    float ntf[8] = {n0.x, n0.y, n0.z, n0.w, n1.x, n1.y, n1.z, n1.w};
    union { unsigned int u[4]; short8_t v; } A;
    #pragma unroll
    for (int p = 0; p < 4; ++p) {
      int e0 = 2 * p, e1 = 2 * p + 1;
      float x0 = f1v + f2v[e0]; x0 = fmaxf(x0, 0.2f * x0);
      float u0 = ((m8 >> e0) & 1u) ? __expf(x0 * ntf[e0]) : 0.0f;
      float x1 = f1v + f2v[e1]; x1 = fmaxf(x1, 0.2f * x1);
      float u1 = ((m8 >> e1) & 1u) ? __expf(x1 * ntf[e1]) : 0.0f;
      A.u[p] = (unsigned int)f2bf(u0) | ((unsigned int)f2bf(u1) << 16);
    }
    const unsigned short* vb = vf + (size_t)(b * 64 + kk) * 2048 + l * 8;
    short8_t bf0 = *(const short8_t*)(vb);
    short8_t bf1 = *(const short8_t*)(vb + 512);
    short8_t bf2 = *(const short8_t*)(vb + 1024);
    short8_t bf3 = *(const short8_t*)(vb + 1536);
    acc0 = __builtin_amdgcn_mfma_f32_16x16x32_bf16(A.v, bf0, acc0, 0, 0, 0);
    acc1 = __builtin_amdgcn_mfma_f32_16x16x32_bf16(A.v, bf1, acc1, 0, 0, 0);
    acc2 = __builtin_amdgcn_mfma_f32_16x16x32_bf16(A.v, bf2, acc2, 0, 0, 0);
    acc3 = __builtin_amdgcn_mfma_f32_16x16x32_bf16(A.v, bf3, acc3, 0, 0, 0);
  }

  #pragma unroll
  for (int r = 0; r < 4; ++r) {
    int rowi = quad * 4 + r;
    red[w * 1088 + rowi * 68 + 0 + col] = acc0[r];
    red[w * 1088 + rowi * 68 + 16 + col] = acc1[r];
    red[w * 1088 + rowi * 68 + 32 + col] = acc2[r];
    red[w * 1088 + rowi * 68 + 48 + col] = acc3[r];
  }
  __syncthreads();

  int row = t >> 4, o4 = (t & 15) * 4;
  const float* rp = &red[row * 68 + o4];
  float4 s0 = *(const float4*)(rp);
  float4 s1 = *(const float4*)(rp + 1088);
  float4 s2 = *(const float4*)(rp + 2176);
  float4 s3 = *(const float4*)(rp + 3264);
  float4 o;
  o.x = fmaxf(s0.x + s1.x + s2.x + s3.x, 0.0f);
  o.y = fmaxf(s0.y + s1.y + s2.y + s3.y, 0.0f);
  o.z = fmaxf(s0.z + s1.z + s2.z + s3.z, 0.0f);
  o.w = fmaxf(s0.w + s1.w + s2.w + s3.w, 0.0f);
  *(float4*)&outp[(size_t)(b * NN + i0 + row) * FO + o4] = o;
}

extern "C" void kernel_launch(void* const* d_in, const int* in_sizes, int n_in,
                              void* d_out, int out_size, void* d_ws, size_t ws_size,
                              hipStream_t stream) {
  const float* h = (const float*)d_in[0];       // fp32 [B,N,FIN]
  const int* adj = (const int*)d_in[1];         // int32 [B,N,N]
  const float* level = (const float*)d_in[2];   // fp32 [B,N]
  const float* ntm = (const float*)d_in[3];     // fp32 [B,N,N]
  const float* W = (const float*)d_in[4];       // fp32 [FIN,FO]
  const float* a = (const float*)d_in[5];       // fp32 [2*FO,1]
  float* outp = (float*)d_out;

  float* V = (float*)d_ws;                              // 4 MB
  float* f1 = V + (size_t)BB * NN * FO;                 // 64 KB
  float* f2 = f1 + BB * NN;                             // 64 KB
  float* scol = f2 + BB * NN;                           // 64 KB
  unsigned short* vf = (unsigned short*)(scol + BB * NN); // 2 MB
  char* tail = (char*)(vf + (size_t)BB * NN * FO);
  size_t fixed = (size_t)(tail - (char*)d_ws);
  size_t need_u = fixed + (size_t)BB * NN * NN * 2;     // + 67 MB
  bool big = (ws_size >= need_u);

  k1_gemm<<<1024, 256, 0, stream>>>(h, level, W, a, V, f1, f2, scol);
  if (big) {
    unsigned short* u_bf = (unsigned short*)tail;
    k2a_stats<1><<<512, 512, 0, stream>>>(adj, ntm, f1, f2, u_bf, nullptr, scol);
    k2b_pack<<<512, 256, 0, stream>>>(V, scol, vf);
    k3_agg_u2<<<256, 512, 0, stream>>>(u_bf, vf, outp);
  } else {
    unsigned char* bits = (unsigned char*)tail;         // + 4 MB
    k2a_stats<0><<<512, 512, 0, stream>>>(adj, ntm, f1, f2, nullptr, bits, scol);
    k2b_pack<<<512, 256, 0, stream>>>(V, scol, vf);
    k3_agg_b<<<1024, 256, 0, stream>>>(ntm, bits, f1, f2, vf, outp);
  }
}

// Round 9
// 335.518 us; speedup vs baseline: 1.1320x; 1.0165x over previous
//
#include <hip/hip_runtime.h>

#define BB 8
#define NN 2048
#define FIN 256
#define FO 64

typedef short short8_t __attribute__((ext_vector_type(8)));
typedef float float4_t __attribute__((ext_vector_type(4)));

__device__ __forceinline__ unsigned short f2bf(float x) {
  unsigned int u = __float_as_uint(x);
  unsigned int r = (u + 0x7fffu + ((u >> 16) & 1u)) >> 16;
  return (unsigned short)r;
}

#define GLD16(gp, lp)                                                          \
  __builtin_amdgcn_global_load_lds(                                            \
      (const __attribute__((address_space(1))) void*)(gp),                     \
      (__attribute__((address_space(3))) void*)(lp), 16, 0, 0)

// ---------------- K1: Wh = h@W ; f1 ; f2 ; V = Wh*level ; zero scol ---------
__global__ __launch_bounds__(256) void k1_gemm(
    const float* __restrict__ h,
    const float* __restrict__ level,
    const float* __restrict__ W,
    const float* __restrict__ a,
    float* __restrict__ V, float* __restrict__ f1, float* __restrict__ f2,
    float* __restrict__ scol)
{
  __shared__ float wlds[128 * 64];
  __shared__ float hs[16 * 260];
  __shared__ float parts1[16 * 17];
  __shared__ float parts2[16 * 17];
  int t = threadIdx.x;
  int b = blockIdx.x >> 7;
  int i0 = (blockIdx.x & 127) * 16;

  if (blockIdx.x < 64) scol[blockIdx.x * 256 + t] = 0.0f;  // folded k0

  {
    int r_ld = t >> 4, f0 = (t & 15) * 16;
    const float* hp = h + (size_t)(b * NN + i0 + r_ld) * FIN + f0;
    float4 x0 = *(const float4*)(hp);
    float4 x1 = *(const float4*)(hp + 4);
    float4 x2 = *(const float4*)(hp + 8);
    float4 x3 = *(const float4*)(hp + 12);
    float* hd = &hs[r_ld * 260 + f0];
    *(float4*)(hd + 0) = x0; *(float4*)(hd + 4) = x1;
    *(float4*)(hd + 8) = x2; *(float4*)(hd + 12) = x3;
  }

  int r = t >> 4;
  int c4 = (t & 15) * 4;
  float4 acc = {0, 0, 0, 0};

  #pragma unroll
  for (int half = 0; half < 2; ++half) {
    __syncthreads();
    #pragma unroll
    for (int q = 0; q < 8; ++q) {
      int idx = q * 1024 + t * 4;
      *(float4*)&wlds[idx] = *(const float4*)&W[half * 8192 + idx];
    }
    __syncthreads();
    for (int f = 0; f < 128; f += 8) {
      float4 hv0 = *(const float4*)&hs[r * 260 + half * 128 + f];
      float4 hv1 = *(const float4*)&hs[r * 260 + half * 128 + f + 4];
      float hvv[8] = {hv0.x, hv0.y, hv0.z, hv0.w, hv1.x, hv1.y, hv1.z, hv1.w};
      #pragma unroll
      for (int k = 0; k < 8; ++k) {
        float4 wv = *(const float4*)&wlds[(f + k) * 64 + c4];
        acc.x += hvv[k] * wv.x; acc.y += hvv[k] * wv.y;
        acc.z += hvv[k] * wv.z; acc.w += hvv[k] * wv.w;
      }
    }
  }

  float p1 = acc.x * a[c4] + acc.y * a[c4 + 1] + acc.z * a[c4 + 2] + acc.w * a[c4 + 3];
  float p2 = acc.x * a[64 + c4] + acc.y * a[64 + c4 + 1] +
             acc.z * a[64 + c4 + 2] + acc.w * a[64 + c4 + 3];
  parts1[r * 17 + (t & 15)] = p1;
  parts2[r * 17 + (t & 15)] = p2;
  __syncthreads();
  if (t < 16) {
    float s1 = 0.f, s2 = 0.f;
    #pragma unroll
    for (int g = 0; g < 16; ++g) { s1 += parts1[t * 17 + g]; s2 += parts2[t * 17 + g]; }
    f1[b * NN + i0 + t] = s1;
    f2[b * NN + i0 + t] = s2;
  }

  float lv = level[b * NN + i0 + r];
  float4 vv = {acc.x * lv, acc.y * lv, acc.z * lv, acc.w * lv};
  *(float4*)&V[(size_t)(b * NN + i0 + r) * FO + c4] = vv;
}

// ---------------- K2a: column sums + u (row-major, coalesced stores) --------
// grid 512 (8 b x 64 32-row spans), 512 threads, DMA double-buffered.
// u stored ROW-MAJOR [b][i][j]: each wave store = 128 B contiguous.
template <int STORE_U>
__global__ __launch_bounds__(512) void k2a_stats(
    const int* __restrict__ adj,
    const float* __restrict__ ntp,
    const float* __restrict__ f1,
    const float* __restrict__ f2,
    unsigned short* __restrict__ u_bf,
    unsigned char* __restrict__ bits,
    float* __restrict__ scol)
{
  __shared__ int ladj[2][16 * 256];   // 32 KB
  __shared__ float lnt[2][16 * 256];  // 32 KB
  __shared__ float red[2048];         // 8 KB
  int t = threadIdx.x;
  int b = blockIdx.x >> 6;
  int row0 = (blockIdx.x & 63) * 32;
  int w = t >> 6, l = t & 63;
  size_t base = (size_t)b * NN;

  auto stage = [&](int buf, int s) {
    int tile = s >> 3, c = s & 7;
    int r0 = row0 + tile * 16 + 2 * w;
    const int* ga = adj + (base + r0) * NN + c * 256 + l * 4;
    const float* gn = ntp + (base + r0) * NN + c * 256 + l * 4;
    GLD16(ga, &ladj[buf][(2 * w) * 256]);
    GLD16(ga + NN, &ladj[buf][(2 * w + 1) * 256]);
    GLD16(gn, &lnt[buf][(2 * w) * 256]);
    GLD16(gn + NN, &lnt[buf][(2 * w + 1) * 256]);
  };

  int jj = t & 255;
  int rh = t >> 8;

  float accJ[8];
  #pragma unroll
  for (int c = 0; c < 8; ++c) accJ[c] = 0.f;
  float f2v[8];
  #pragma unroll
  for (int c = 0; c < 8; ++c) f2v[c] = f2[base + c * 256 + jj];

  stage(0, 0);
  for (int s = 0; s < 16; ++s) {
    int buf = s & 1;
    __syncthreads();
    if (s < 15) stage(buf ^ 1, s + 1);
    int tile = s >> 3, c = s & 7;
    #pragma unroll
    for (int q = 0; q < 8; ++q) {
      int r = rh * 8 + q;
      int av = ladj[buf][r * 256 + jj];
      float nv = lnt[buf][r * 256 + jj];
      float f1v = f1[base + row0 + tile * 16 + r];
      float x = f1v + f2v[c];
      x = fmaxf(x, 0.2f * x);            // leaky_relu slope 0.2
      bool m = av > 0;
      float u = m ? __expf(x * nv) : 0.0f;
      accJ[c] += u;
      if (STORE_U) {
        u_bf[(base + row0 + tile * 16 + r) * NN + c * 256 + jj] = f2bf(u);
      } else {
        unsigned long long bal = __ballot(m);
        if (l == 0)
          *(unsigned long long*)&bits[(base + row0 + tile * 16 + r) * (NN / 8)
                                      + c * 32 + (w & 3) * 8] = bal;
      }
    }
  }

  if (rh == 0) {
    #pragma unroll
    for (int c = 0; c < 8; ++c) red[c * 256 + jj] = accJ[c];
  }
  __syncthreads();
  if (rh == 1) {
    #pragma unroll
    for (int c = 0; c < 8; ++c) red[c * 256 + jj] += accJ[c];
  }
  __syncthreads();
  #pragma unroll
  for (int q = 0; q < 4; ++q)
    atomicAdd(&scol[base + q * 512 + t], red[q * 512 + t]);
}

// ---------------- K2b: pack V'[j][o]=V[j][o]/s_j into MFMA B-frag order -----
__global__ __launch_bounds__(256) void k2b_pack(
    const float* __restrict__ V,
    const float* __restrict__ scol,
    unsigned short* __restrict__ vf)
{
  int t = threadIdx.x;
  int b = blockIdx.x >> 6;
  int kk = blockIdx.x & 63;
  int ng = t >> 6;
  int l = t & 63;
  int jb = kk * 32 + ((l >> 4) * 8);
  int o = ng * 16 + (l & 15);
  unsigned int pk[4];
  #pragma unroll
  for (int p = 0; p < 4; ++p) {
    int jr0 = jb + 2 * p, jr1 = jb + 2 * p + 1;
    float s0 = scol[b * NN + jr0];
    float s1 = scol[b * NN + jr1];
    float i0 = (s0 > 0.f) ? (1.0f / s0) : 0.0f;
    float i1 = (s1 > 0.f) ? (1.0f / s1) : 0.0f;
    float v0 = V[(size_t)(b * NN + jr0) * FO + o] * i0;
    float v1 = V[(size_t)(b * NN + jr1) * FO + o] * i1;
    pk[p] = (unsigned int)f2bf(v0) | ((unsigned int)f2bf(v1) << 16);
  }
  *(uint4*)(vf + (size_t)(((b * 64 + kk) * 4 + ng) * 64 + l) * 8) =
      make_uint4(pk[0], pk[1], pk[2], pk[3]);
}

// ---------------- K3: out = relu(U @ V'), 32-row tiles, 16 waves/CU ---------
// grid 512 (8 b x 64 tiles of 32 rows), 512 threads = 8 waves, 2 blocks/CU.
// Wave w owns kk = w*8..w*8+7; 2 sub-tiles of 16 rows; depth-1 prefetch on
// A and vf; 8-way cross-wave k-reduce in LDS.
__global__ __launch_bounds__(512, 4) void k3_agg_u3(
    const unsigned short* __restrict__ u_bf,
    const unsigned short* __restrict__ vf,
    float* __restrict__ outp)
{
  __shared__ float red[8 * 16 * 68];   // 34.8 KB
  int t = threadIdx.x;
  int b = blockIdx.x >> 6;
  int tt = blockIdx.x & 63;
  int i0 = tt * 32;
  int w = t >> 6, l = t & 63;
  int col = l & 15, quad = l >> 4;
  const unsigned short* urow0 = u_bf + (size_t)(b * NN + i0 + col) * NN + quad * 8;
  const unsigned short* urow1 = urow0 + (size_t)16 * NN;
  const unsigned short* vbase = vf + (size_t)(b * 64) * 2048 + l * 8;

  float4_t acc[2][4];
  #pragma unroll
  for (int sgi = 0; sgi < 2; ++sgi)
    #pragma unroll
    for (int g = 0; g < 4; ++g) acc[sgi][g] = (float4_t){0, 0, 0, 0};

  int kk0 = w * 8;
  short8_t A0 = *(const short8_t*)(urow0 + kk0 * 32);
  short8_t A1 = *(const short8_t*)(urow1 + kk0 * 32);
  const unsigned short* vb0 = vbase + (size_t)kk0 * 2048;
  short8_t c0 = *(const short8_t*)(vb0);
  short8_t c1 = *(const short8_t*)(vb0 + 512);
  short8_t c2 = *(const short8_t*)(vb0 + 1024);
  short8_t c3 = *(const short8_t*)(vb0 + 1536);

  #pragma unroll
  for (int s = 0; s < 8; ++s) {
    short8_t nA0, nA1, n0, n1, n2, n3;
    if (s < 7) {
      int kk = w * 8 + s + 1;
      nA0 = *(const short8_t*)(urow0 + kk * 32);
      nA1 = *(const short8_t*)(urow1 + kk * 32);
      const unsigned short* vn = vbase + (size_t)kk * 2048;
      n0 = *(const short8_t*)(vn);
      n1 = *(const short8_t*)(vn + 512);
      n2 = *(const short8_t*)(vn + 1024);
      n3 = *(const short8_t*)(vn + 1536);
    }
    acc[0][0] = __builtin_amdgcn_mfma_f32_16x16x32_bf16(A0, c0, acc[0][0], 0, 0, 0);
    acc[0][1] = __builtin_amdgcn_mfma_f32_16x16x32_bf16(A0, c1, acc[0][1], 0, 0, 0);
    acc[0][2] = __builtin_amdgcn_mfma_f32_16x16x32_bf16(A0, c2, acc[0][2], 0, 0, 0);
    acc[0][3] = __builtin_amdgcn_mfma_f32_16x16x32_bf16(A0, c3, acc[0][3], 0, 0, 0);
    acc[1][0] = __builtin_amdgcn_mfma_f32_16x16x32_bf16(A1, c0, acc[1][0], 0, 0, 0);
    acc[1][1] = __builtin_amdgcn_mfma_f32_16x16x32_bf16(A1, c1, acc[1][1], 0, 0, 0);
    acc[1][2] = __builtin_amdgcn_mfma_f32_16x16x32_bf16(A1, c2, acc[1][2], 0, 0, 0);
    acc[1][3] = __builtin_amdgcn_mfma_f32_16x16x32_bf16(A1, c3, acc[1][3], 0, 0, 0);
    if (s < 7) { A0 = nA0; A1 = nA1; c0 = n0; c1 = n1; c2 = n2; c3 = n3; }
  }

  #pragma unroll
  for (int sub = 0; sub < 2; ++sub) {
    __syncthreads();
    #pragma unroll
    for (int r = 0; r < 4; ++r) {
      int rowi = quad * 4 + r;
      float* rp = &red[w * 1088 + rowi * 68 + col];
      rp[0] = acc[sub][0][r];
      rp[16] = acc[sub][1][r];
      rp[32] = acc[sub][2][r];
      rp[48] = acc[sub][3][r];
    }
    __syncthreads();
    if (t < 256) {
      int row = t >> 4, o4 = (t & 15) * 4;
      const float* rp = &red[row * 68 + o4];
      float4 s0 = *(const float4*)(rp);
      float4 s1 = *(const float4*)(rp + 1088);
      float4 s2 = *(const float4*)(rp + 2176);
      float4 s3 = *(const float4*)(rp + 3264);
      float4 s4 = *(const float4*)(rp + 4352);
      float4 s5 = *(const float4*)(rp + 5440);
      float4 s6 = *(const float4*)(rp + 6528);
      float4 s7 = *(const float4*)(rp + 7616);
      float4 o;
      o.x = fmaxf(s0.x + s1.x + s2.x + s3.x + s4.x + s5.x + s6.x + s7.x, 0.0f);
      o.y = fmaxf(s0.y + s1.y + s2.y + s3.y + s4.y + s5.y + s6.y + s7.y, 0.0f);
      o.z = fmaxf(s0.z + s1.z + s2.z + s3.z + s4.z + s5.z + s6.z + s7.z, 0.0f);
      o.w = fmaxf(s0.w + s1.w + s2.w + s3.w + s4.w + s5.w + s6.w + s7.w, 0.0f);
      *(float4*)&outp[(size_t)(b * NN + i0 + sub * 16 + row) * FO + o4] = o;
    }
  }
}

// ---------------- K3b: fallback — recompute u from nt/f1/f2/bits -----------
__global__ __launch_bounds__(256) void k3_agg_b(
    const float* __restrict__ ntp,
    const unsigned char* __restrict__ bits,
    const float* __restrict__ f1,
    const float* __restrict__ f2,
    const unsigned short* __restrict__ vf,
    float* __restrict__ outp)
{
  __shared__ float red[4 * 16 * 68];
  int t = threadIdx.x;
  int b = blockIdx.x >> 7;
  int i0 = (blockIdx.x & 127) * 16;
  int w = t >> 6, l = t & 63;
  int col = l & 15, quad = l >> 4;
  int gi = b * NN + i0 + col;
  float f1v = f1[gi];
  const float* ntrow = ntp + (size_t)gi * NN;
  const unsigned char* brow = bits + (size_t)gi * (NN / 8);
  float4_t acc0 = {0, 0, 0, 0}, acc1 = {0, 0, 0, 0}, acc2 = {0, 0, 0, 0}, acc3 = {0, 0, 0, 0};

  for (int s = 0; s < 16; ++s) {
    int kk = w * 16 + s;
    int jq = kk * 32 + quad * 8;
    unsigned int m8 = brow[jq >> 3];
    float4 n0 = *(const float4*)(ntrow + jq);
    float4 n1 = *(const float4*)(ntrow + jq + 4);
    float4 g0 = *(const float4*)(f2 + b * NN + jq);
    float4 g1 = *(const float4*)(f2 + b * NN + jq + 4);
    float f2v[8] = {g0.x, g0.y, g0.z, g0.w, g1.x, g1.y, g1.z, g1.w};
    float ntf[8] = {n0.x, n0.y, n0.z, n0.w, n1.x, n1.y, n1.z, n1.w};
    union { unsigned int u[4]; short8_t v; } A;
    #pragma unroll
    for (int p = 0; p < 4; ++p) {
      int e0 = 2 * p, e1 = 2 * p + 1;
      float x0 = f1v + f2v[e0]; x0 = fmaxf(x0, 0.2f * x0);
      float u0 = ((m8 >> e0) & 1u) ? __expf(x0 * ntf[e0]) : 0.0f;
      float x1 = f1v + f2v[e1]; x1 = fmaxf(x1, 0.2f * x1);
      float u1 = ((m8 >> e1) & 1u) ? __expf(x1 * ntf[e1]) : 0.0f;
      A.u[p] = (unsigned int)f2bf(u0) | ((unsigned int)f2bf(u1) << 16);
    }
    const unsigned short* vb = vf + (size_t)(b * 64 + kk) * 2048 + l * 8;
    short8_t bf0 = *(const short8_t*)(vb);
    short8_t bf1 = *(const short8_t*)(vb + 512);
    short8_t bf2 = *(const short8_t*)(vb + 1024);
    short8_t bf3 = *(const short8_t*)(vb + 1536);
    acc0 = __builtin_amdgcn_mfma_f32_16x16x32_bf16(A.v, bf0, acc0, 0, 0, 0);
    acc1 = __builtin_amdgcn_mfma_f32_16x16x32_bf16(A.v, bf1, acc1, 0, 0, 0);
    acc2 = __builtin_amdgcn_mfma_f32_16x16x32_bf16(A.v, bf2, acc2, 0, 0, 0);
    acc3 = __builtin_amdgcn_mfma_f32_16x16x32_bf16(A.v, bf3, acc3, 0, 0, 0);
  }

  #pragma unroll
  for (int r = 0; r < 4; ++r) {
    int rowi = quad * 4 + r;
    red[w * 1088 + rowi * 68 + 0 + col] = acc0[r];
    red[w * 1088 + rowi * 68 + 16 + col] = acc1[r];
    red[w * 1088 + rowi * 68 + 32 + col] = acc2[r];
    red[w * 1088 + rowi * 68 + 48 + col] = acc3[r];
  }
  __syncthreads();

  int row = t >> 4, o4 = (t & 15) * 4;
  const float* rp = &red[row * 68 + o4];
  float4 s0 = *(const float4*)(rp);
  float4 s1 = *(const float4*)(rp + 1088);
  float4 s2 = *(const float4*)(rp + 2176);
  float4 s3 = *(const float4*)(rp + 3264);
  float4 o;
  o.x = fmaxf(s0.x + s1.x + s2.x + s3.x, 0.0f);
  o.y = fmaxf(s0.y + s1.y + s2.y + s3.y, 0.0f);
  o.z = fmaxf(s0.z + s1.z + s2.z + s3.z, 0.0f);
  o.w = fmaxf(s0.w + s1.w + s2.w + s3.w, 0.0f);
  *(float4*)&outp[(size_t)(b * NN + i0 + row) * FO + o4] = o;
}

extern "C" void kernel_launch(void* const* d_in, const int* in_sizes, int n_in,
                              void* d_out, int out_size, void* d_ws, size_t ws_size,
                              hipStream_t stream) {
  const float* h = (const float*)d_in[0];       // fp32 [B,N,FIN]
  const int* adj = (const int*)d_in[1];         // int32 [B,N,N]
  const float* level = (const float*)d_in[2];   // fp32 [B,N]
  const float* ntm = (const float*)d_in[3];     // fp32 [B,N,N]
  const float* W = (const float*)d_in[4];       // fp32 [FIN,FO]
  const float* a = (const float*)d_in[5];       // fp32 [2*FO,1]
  float* outp = (float*)d_out;

  float* V = (float*)d_ws;                              // 4 MB
  float* f1 = V + (size_t)BB * NN * FO;                 // 64 KB
  float* f2 = f1 + BB * NN;                             // 64 KB
  float* scol = f2 + BB * NN;                           // 64 KB
  unsigned short* vf = (unsigned short*)(scol + BB * NN); // 2 MB
  char* tail = (char*)(vf + (size_t)BB * NN * FO);
  size_t fixed = (size_t)(tail - (char*)d_ws);
  size_t need_u = fixed + (size_t)BB * NN * NN * 2;     // + 67 MB
  bool big = (ws_size >= need_u);

  k1_gemm<<<1024, 256, 0, stream>>>(h, level, W, a, V, f1, f2, scol);
  if (big) {
    unsigned short* u_bf = (unsigned short*)tail;
    k2a_stats<1><<<512, 512, 0, stream>>>(adj, ntm, f1, f2, u_bf, nullptr, scol);
    k2b_pack<<<512, 256, 0, stream>>>(V, scol, vf);
    k3_agg_u3<<<512, 512, 0, stream>>>(u_bf, vf, outp);
  } else {
    unsigned char* bits = (unsigned char*)tail;         // + 4 MB
    k2a_stats<0><<<512, 512, 0, stream>>>(adj, ntm, f1, f2, nullptr, bits, scol);
    k2b_pack<<<512, 256, 0, stream>>>(V, scol, vf);
    k3_agg_b<<<1024, 256, 0, stream>>>(ntm, bits, f1, f2, vf, outp);
  }
}